// Round 3
// baseline (341.343 us; speedup 1.0000x reference)
//
#include <hip/hip_runtime.h>

// MultiHeadedAttention B=2,S=2048,D=1024,H=16,Dh=64 — f32 in/out.
// Round 10 (V direct-to-register):
//   - Vs LDS staging DELETED. PV B-fragments load straight from Vt global
//     (L2-resident, 256KB/head) into VGPRs at the TOP of each iteration,
//     consumed at the bottom (PV) — full-body latency hiding, per-wave
//     counted vmcnt waits from the compiler, no barrier coupling.
//     The XOR swizzle cancels for the direct read:
//       vf[kh][nt] = Vt[vbase + (nt*16+x)*SEQ + k0 + kh*32 + y*8].
//   - Issue order mask -> vf -> K-stage == consumption order (softmax ->
//     PV -> next iter), so no vmcnt wait retires a younger load early.
//   - LDS 40 -> 24 KB; K stays double-buffered, one __syncthreads per iter.
// Round 9: K/V dbuf, single barrier. Round 8: exp2-direct softmax, additive
// mask-bias plane, v_cvt_pk_bf16_f32 P-pack.
// MFMA frag layouts + XOR-slot swizzle hardware-verified (rounds 3-6).

typedef unsigned short ushort_t;
typedef __attribute__((ext_vector_type(8))) short short8;
typedef __attribute__((ext_vector_type(4))) float floatx4;

#define BATCH 2
#define SEQ   2048
#define DF    1024
#define NH    16
#define DH    64
#define MROWS 4096

__device__ __forceinline__ float bf2f(ushort_t u) {
    return __uint_as_float(((unsigned int)u) << 16);
}
__device__ __forceinline__ ushort_t f2bf(float f) {
    unsigned int u = __float_as_uint(f);
    u += 0x7FFFu + ((u >> 16) & 1u);   // RNE
    return (ushort_t)(u >> 16);
}

__device__ __forceinline__ float exp2_fast(float x) {
#if defined(__has_builtin)
#if __has_builtin(__builtin_amdgcn_exp2f)
    return __builtin_amdgcn_exp2f(x);
#else
    float r; asm("v_exp_f32 %0, %1" : "=v"(r) : "v"(x)); return r;
#endif
#else
    float r; asm("v_exp_f32 %0, %1" : "=v"(r) : "v"(x)); return r;
#endif
}

// ---------------------------------------------------------------------------
// Fused f32->bf16 conversion of 7 tensors + int-mask -> float-bias plane.
// ---------------------------------------------------------------------------
struct CvtArgs {
    const float* src[7];
    ushort_t*    dst[7];
    int          n[7];
    const int*   msrc;   // int mask  [B*S]
    float*       mdst;   // float bias [B*S]: mask? 0 : -1e9
};

__global__ __launch_bounds__(256) void cvt_all(CvtArgs a)
{
    const int y = blockIdx.y;
    if (y == 7) {
        int i = (blockIdx.x * 256 + threadIdx.x) * 4;
        if (i >= BATCH * SEQ) return;
        int4 m = *(const int4*)(a.msrc + i);
        float4 o;
        o.x = m.x ? 0.f : -1e9f;
        o.y = m.y ? 0.f : -1e9f;
        o.z = m.z ? 0.f : -1e9f;
        o.w = m.w ? 0.f : -1e9f;
        *(float4*)(a.mdst + i) = o;
        return;
    }
    const int n = a.n[y];
    int i = (blockIdx.x * 256 + threadIdx.x) * 4;
    if (i >= n) return;
    const float* in = a.src[y];
    ushort_t* out = a.dst[y];
    float4 v = *(const float4*)(in + i);
    ushort4 o;
    o.x = f2bf(v.x); o.y = f2bf(v.y); o.z = f2bf(v.z); o.w = f2bf(v.w);
    *(ushort4*)(out + i) = o;
}

// ---------------------------------------------------------------------------
// Fused QKV projections, all-bf16 operands. Grid (24,32): n0 = bx*128.
//   n0 <1024: Qf (A=Qb, bq, epilogue scale log2e/32 — folds softmax scale AND
//             the exp->exp2 conversion)
//   <2048:    Kf (A=Kb, bk)
//   else:     Vt DIRECT (A=Vb, bv) — transposed write [(b*16+h)*64+dh][s],
//             thread's 4 acc regs per (mt,nt) are 4 consecutive s -> ushort4.
// 128x128 tile, BK=64, global_load_lds staging, XOR-slot swizzle (verified).
// ---------------------------------------------------------------------------
__global__ __launch_bounds__(256) void gemm_qkv(
    const ushort_t* __restrict__ Qb, const ushort_t* __restrict__ Kb,
    const ushort_t* __restrict__ Vb, const ushort_t* __restrict__ Wcat,
    const float* __restrict__ bq, const float* __restrict__ bk,
    const float* __restrict__ bv,
    ushort_t* __restrict__ Qf, ushort_t* __restrict__ Kf,
    ushort_t* __restrict__ Vt)
{
    __shared__ ushort_t As[128 * 64];  // 16 KB, [row][slot], slot = k8 ^ (row&7)
    __shared__ ushort_t Bs[128 * 64];  // 16 KB

    const int t = threadIdx.x;
    const int lane = t & 63, w = t >> 6;
    const int x = lane & 15, y = lane >> 4;
    const int wm = (w >> 1) * 64, wn = (w & 1) * 64;
    const int m0 = blockIdx.y << 7, n0 = blockIdx.x << 7;

    const ushort_t* Ab; const float* bp;
    if (n0 < 1024)      { Ab = Qb; bp = bq; }
    else if (n0 < 2048) { Ab = Kb; bp = bk; }
    else                { Ab = Vb; bp = bv; }
    const int ncol0 = n0 & 1023;

    floatx4 acc[4][4] = {};

    for (int kt = 0; kt < 16; ++kt) {
        const int k0 = kt * 64;

        #pragma unroll
        for (int j = 0; j < 4; ++j) {   // A stage
            int i   = (w << 2) + j;
            int c   = (i << 6) + lane;
            int row = c >> 3;
            int s   = c & 7;
            int k8  = s ^ (row & 7);
            const ushort_t* g = Ab + (size_t)(m0 + row) * DF + k0 + (k8 << 3);
            __builtin_amdgcn_global_load_lds(
                (const __attribute__((address_space(1))) unsigned int*)g,
                (__attribute__((address_space(3))) unsigned int*)(As + (i << 9)),
                16, 0, 0);
        }
        #pragma unroll
        for (int j = 0; j < 4; ++j) {   // B stage
            int i   = (w << 2) + j;
            int c   = (i << 6) + lane;
            int row = c >> 3;
            int s   = c & 7;
            int k8  = s ^ (row & 7);
            const ushort_t* g = Wcat + (size_t)(n0 + row) * DF + k0 + (k8 << 3);
            __builtin_amdgcn_global_load_lds(
                (const __attribute__((address_space(1))) unsigned int*)g,
                (__attribute__((address_space(3))) unsigned int*)(Bs + (i << 9)),
                16, 0, 0);
        }
        __syncthreads();

        #pragma unroll
        for (int kh = 0; kh < 2; ++kh) {
            const int slot = ((kh << 2) + y) ^ (x & 7);
            short8 af[4], bfr[4];
            #pragma unroll
            for (int mt = 0; mt < 4; ++mt)
                af[mt] = *(const short8*)(As + (wm + (mt << 4) + x) * 64 + slot * 8);
            #pragma unroll
            for (int nt = 0; nt < 4; ++nt)
                bfr[nt] = *(const short8*)(Bs + (wn + (nt << 4) + x) * 64 + slot * 8);
            #pragma unroll
            for (int mt = 0; mt < 4; ++mt)
                #pragma unroll
                for (int nt = 0; nt < 4; ++nt)
                    acc[mt][nt] = __builtin_amdgcn_mfma_f32_16x16x32_bf16(
                        af[mt], bfr[nt], acc[mt][nt], 0, 0, 0);
        }
        __syncthreads();
    }

    float bvv[4];
    #pragma unroll
    for (int nt = 0; nt < 4; ++nt) bvv[nt] = bp[ncol0 + wn + (nt << 4) + x];

    if (n0 < 2048) {
        // Qf/Kf: natural layout, scale log2e/32 for Q (softmax scale + exp2 fold)
        ushort_t* outp = (n0 < 1024) ? Qf : Kf;
        const float osc = (n0 < 1024) ? 0.0450842200f : 1.0f;  // log2(e)/32
        #pragma unroll
        for (int mt = 0; mt < 4; ++mt) {
            #pragma unroll
            for (int r = 0; r < 4; ++r) {
                const size_t grow = (size_t)(m0 + wm + (mt << 4) + (y << 2) + r) * DF;
                #pragma unroll
                for (int nt = 0; nt < 4; ++nt)
                    outp[grow + ncol0 + wn + (nt << 4) + x] =
                        f2bf((acc[mt][nt][r] + bvv[nt]) * osc);
            }
        }
    } else {
        // V: direct transposed write to Vt[(b*16+h)*64+dh][s]
        #pragma unroll
        for (int mt = 0; mt < 4; ++mt) {
            int m   = m0 + wm + (mt << 4) + (y << 2);  // +r are consecutive s
            int bb2 = m >> 11;
            int s0  = m & 2047;
            #pragma unroll
            for (int nt = 0; nt < 4; ++nt) {
                int col = ncol0 + wn + (nt << 4) + x;  // h*64+dh
                ushort4 pk;
                pk.x = f2bf(acc[mt][nt][0] + bvv[nt]);
                pk.y = f2bf(acc[mt][nt][1] + bvv[nt]);
                pk.z = f2bf(acc[mt][nt][2] + bvv[nt]);
                pk.w = f2bf(acc[mt][nt][3] + bvv[nt]);
                *(ushort4*)(Vt + ((size_t)(bb2 << 10) + col) * 2048 + s0) = pk;
            }
        }
    }
}

// ---------------------------------------------------------------------------
// Out-projection: C[4096,1024] = Xr @ Wo^T + bo, f32 out.
// Tile 128(M) x 64(N), grid (16,32) = 512 blocks = 2/CU. Wave-tile 64x32.
// ---------------------------------------------------------------------------
__global__ __launch_bounds__(256) void gemm_out(
    const ushort_t* __restrict__ Xr, const ushort_t* __restrict__ Wb,
    const float* __restrict__ bias, float* __restrict__ C)
{
    __shared__ ushort_t As[128 * 64];  // 16 KB
    __shared__ ushort_t Bs[64 * 64];   // 8 KB

    const int t = threadIdx.x;
    const int lane = t & 63, w = t >> 6;
    const int x = lane & 15, y = lane >> 4;
    const int wm = (w >> 1) * 64, wn = (w & 1) * 32;
    const int m0 = blockIdx.y << 7, n0 = blockIdx.x << 6;

    floatx4 acc[4][2] = {};

    for (int kt = 0; kt < 16; ++kt) {
        const int k0 = kt * 64;

        #pragma unroll
        for (int j = 0; j < 4; ++j) {   // A stage: 16 KB
            int i   = (w << 2) + j;
            int c   = (i << 6) + lane;
            int row = c >> 3;
            int s   = c & 7;
            int k8  = s ^ (row & 7);
            const ushort_t* g = Xr + (size_t)(m0 + row) * DF + k0 + (k8 << 3);
            __builtin_amdgcn_global_load_lds(
                (const __attribute__((address_space(1))) unsigned int*)g,
                (__attribute__((address_space(3))) unsigned int*)(As + (i << 9)),
                16, 0, 0);
        }
        #pragma unroll
        for (int j = 0; j < 2; ++j) {   // B stage: 8 KB
            int i   = (w << 1) + j;
            int c   = (i << 6) + lane;
            int row = c >> 3;
            int s   = c & 7;
            int k8  = s ^ (row & 7);
            const ushort_t* g = Wb + (size_t)(n0 + row) * DF + k0 + (k8 << 3);
            __builtin_amdgcn_global_load_lds(
                (const __attribute__((address_space(1))) unsigned int*)g,
                (__attribute__((address_space(3))) unsigned int*)(Bs + (i << 9)),
                16, 0, 0);
        }
        __syncthreads();

        #pragma unroll
        for (int kh = 0; kh < 2; ++kh) {
            const int slot = ((kh << 2) + y) ^ (x & 7);
            short8 af[4], bfr[2];
            #pragma unroll
            for (int mt = 0; mt < 4; ++mt)
                af[mt] = *(const short8*)(As + (wm + (mt << 4) + x) * 64 + slot * 8);
            #pragma unroll
            for (int nt = 0; nt < 2; ++nt)
                bfr[nt] = *(const short8*)(Bs + (wn + (nt << 4) + x) * 64 + slot * 8);
            #pragma unroll
            for (int mt = 0; mt < 4; ++mt)
                #pragma unroll
                for (int nt = 0; nt < 2; ++nt)
                    acc[mt][nt] = __builtin_amdgcn_mfma_f32_16x16x32_bf16(
                        af[mt], bfr[nt], acc[mt][nt], 0, 0, 0);
        }
        __syncthreads();
    }

    float bvv[2];
    #pragma unroll
    for (int nt = 0; nt < 2; ++nt) bvv[nt] = bias[n0 + wn + (nt << 4) + x];

    #pragma unroll
    for (int mt = 0; mt < 4; ++mt) {
        #pragma unroll
        for (int r = 0; r < 4; ++r) {
            const size_t grow = (size_t)(m0 + wm + (mt << 4) + (y << 2) + r) * DF;
            #pragma unroll
            for (int nt = 0; nt < 2; ++nt)
                C[grow + n0 + wn + (nt << 4) + x] = acc[mt][nt][r] + bvv[nt];
        }
    }
}

// ---------------------------------------------------------------------------
// Attention, full MFMA, S^T variant.
// QK^T swapped: sacc[mt] = mfma(kfrag, qfrag) -> D[row=key][col=q]; thread
// (x,y) owns keys mt*16+y*4..+3 for q=wm+x. Softmax: additive float bias,
// raw v_exp_f32 (scale folded into Q), P packed via v_cvt_pk_bf16_f32 ->
// ds_write_b64. P region wave-local -> no mid barrier.
//
// Pipeline (R10): per iter, issue mask(4) -> vf(8, DIRECT global->reg from
// Vt; swizzle cancels: Vt[dh][k0+kh*32+y*8]) -> K-stage(2, gload_lds to
// buf^1). Consumption order softmax -> PV -> next-iter matches issue order,
// so each compiler vmcnt wait leaves younger loads in flight. One
// __syncthreads per iter (drains the 2 K loads only, issued a full body
// earlier). K double-buffered; Vs deleted. LDS 24 KB.
// ---------------------------------------------------------------------------
__global__ __launch_bounds__(256) void attn_mfma(
    const ushort_t* __restrict__ Qf, const ushort_t* __restrict__ Kf,
    const ushort_t* __restrict__ Vt, const float* __restrict__ maskb,
    ushort_t* __restrict__ Xr)
{
    __shared__ ushort_t Qs[64 * 64];      // 8 KB; becomes Ps after qfrag extract
    __shared__ ushort_t Ks[2][64 * 64];   // 16 KB double-buffered
    ushort_t* Ps = Qs;

    const int t = threadIdx.x;
    const int lane = t & 63, w = t >> 6;
    const int x = lane & 15, y = lane >> 4;
    const int wm = w << 4;
    const int b = blockIdx.z, h = blockIdx.y;
    const int q0 = blockIdx.x << 6;
    const size_t qkbase = ((size_t)b * SEQ) * DF + (size_t)h * DH;
    const size_t vbase  = ((size_t)(b * NH + h) * DH) * SEQ;
    const int mbase = b * SEQ;

    // ---- prologue: Q stage + K tile 0 into buf 0 (8 chunks, 2/wave) ----
    #pragma unroll
    for (int j = 0; j < 2; ++j) {
        int i   = (w << 1) + j;
        int c   = (i << 6) + lane;
        int row = c >> 3;
        int s   = c & 7;
        int k8  = s ^ (row & 7);
        const ushort_t* gq = Qf + qkbase + (size_t)(q0 + row) * DF + (k8 << 3);
        __builtin_amdgcn_global_load_lds(
            (const __attribute__((address_space(1))) unsigned int*)gq,
            (__attribute__((address_space(3))) unsigned int*)(Qs + (i << 9)),
            16, 0, 0);
        const ushort_t* gk = Kf + qkbase + (size_t)row * DF + (k8 << 3);
        __builtin_amdgcn_global_load_lds(
            (const __attribute__((address_space(1))) unsigned int*)gk,
            (__attribute__((address_space(3))) unsigned int*)(Ks[0] + (i << 9)),
            16, 0, 0);
    }
    __syncthreads();

    short8 qfrag[2];
    #pragma unroll
    for (int kh = 0; kh < 2; ++kh) {
        int slot = ((kh << 2) + y) ^ (x & 7);
        qfrag[kh] = *(const short8*)(Qs + (wm + x) * 64 + slot * 8);
    }
    // qfrag ds_reads complete before the first QK^T MFMA (compiler lgkmcnt
    // wait), which precedes the first Ps write in program order; same-wave
    // DS ops complete in order -> no barrier needed before Ps reuse.

    floatx4 oacc[4] = {};
    float dsum = 0.f;

    for (int kt = 0; kt < 32; ++kt) {
        const int cur = kt & 1;
        const int k0 = kt << 6;

        // ---- (1) mask-bias loads for THIS tile ----
        float4 mb[4];
        #pragma unroll
        for (int mt = 0; mt < 4; ++mt)
            mb[mt] = *(const float4*)(maskb + mbase + k0 + (mt << 4) + (y << 2));

        // ---- (2) V fragments DIRECT global->reg (consumed in PV) ----
        short8 vf[2][4];
        #pragma unroll
        for (int kh = 0; kh < 2; ++kh)
            #pragma unroll
            for (int nt = 0; nt < 4; ++nt)
                vf[kh][nt] = *(const short8*)(
                    Vt + vbase + (size_t)((nt << 4) + x) * SEQ
                       + k0 + (kh << 5) + (y << 3));

        // ---- (3) stage NEXT K tile into the other buffer ----
        if (kt < 31) {
            const int k0n = (kt + 1) << 6;
            ushort_t* Kd = Ks[cur ^ 1];
            #pragma unroll
            for (int j = 0; j < 2; ++j) {
                int i   = (w << 1) + j;
                int c   = (i << 6) + lane;
                int row = c >> 3;
                int s   = c & 7;
                int k8  = s ^ (row & 7);
                const ushort_t* g = Kf + qkbase + (size_t)(k0n + row) * DF + (k8 << 3);
                __builtin_amdgcn_global_load_lds(
                    (const __attribute__((address_space(1))) unsigned int*)g,
                    (__attribute__((address_space(3))) unsigned int*)(Kd + (i << 9)),
                    16, 0, 0);
            }
        }

        // ---- S^T = K·Q^T on buf[cur]: D[row=key][col=q] ----
        const ushort_t* Kc = Ks[cur];
        floatx4 sacc[4] = {};
        #pragma unroll
        for (int kh = 0; kh < 2; ++kh) {
            const int slot = ((kh << 2) + y) ^ (x & 7);
            #pragma unroll
            for (int mt = 0; mt < 4; ++mt) {
                short8 kf = *(const short8*)(Kc + ((mt << 4) + x) * 64 + slot * 8);
                sacc[mt] = __builtin_amdgcn_mfma_f32_16x16x32_bf16(
                    kf, qfrag[kh], sacc[mt], 0, 0, 0);
            }
        }

        // ---- softmax: bias-add + exp2 + packed P write (wave-local rows) ----
        #pragma unroll
        for (int mt = 0; mt < 4; ++mt) {
            float p0 = exp2_fast(sacc[mt][0] + mb[mt].x);
            float p1 = exp2_fast(sacc[mt][1] + mb[mt].y);
            float p2 = exp2_fast(sacc[mt][2] + mb[mt].z);
            float p3 = exp2_fast(sacc[mt][3] + mb[mt].w);
            dsum += (p0 + p1) + (p2 + p3);
            unsigned int w0, w1;
            asm("v_cvt_pk_bf16_f32 %0, %1, %2" : "=v"(w0) : "v"(p0), "v"(p1));
            asm("v_cvt_pk_bf16_f32 %0, %1, %2" : "=v"(w1) : "v"(p2), "v"(p3));
            uint2 pk; pk.x = w0; pk.y = w1;
            int slot2 = ((mt << 1) + (y >> 1)) ^ (x & 7);
            *(uint2*)(Ps + ((wm + x) << 6) + (slot2 << 3) + ((y & 1) << 2)) = pk;
        }

        // ---- PV: O strip 16q x 64dh (P from own wave's LDS rows, V regs) ----
        #pragma unroll
        for (int kh = 0; kh < 2; ++kh) {
            const int slot = ((kh << 2) + y) ^ (x & 7);
            short8 pf = *(const short8*)(Ps + (wm + x) * 64 + slot * 8);
            #pragma unroll
            for (int nt = 0; nt < 4; ++nt)
                oacc[nt] = __builtin_amdgcn_mfma_f32_16x16x32_bf16(
                    pf, vf[kh][nt], oacc[nt], 0, 0, 0);
        }

        __syncthreads();   // K tile kt+1 staged & visible; Ks[cur] reads drained
    }

    // dsum: thread holds partial for q=wm+x (keys y*4+r per tile);
    // reduce across the 4 y-lanes sharing x, then broadcast per output row.
    dsum += __shfl_xor(dsum, 16, 64);
    dsum += __shfl_xor(dsum, 32, 64);
    float rdv[4];
    #pragma unroll
    for (int r = 0; r < 4; ++r)
        rdv[r] = 1.0f / __shfl(dsum, (y << 2) + r, 64);

    #pragma unroll
    for (int r = 0; r < 4; ++r) {
        int q = q0 + wm + (y << 2) + r;
        #pragma unroll
        for (int nt = 0; nt < 4; ++nt)
            Xr[qkbase + (size_t)q * DF + (nt << 4) + x] = f2bf(oacc[nt][r] * rdv[r]);
    }
}

// ---------------------------------------------------------------------------
extern "C" void kernel_launch(void* const* d_in, const int* in_sizes, int n_in,
                              void* d_out, int out_size, void* d_ws, size_t ws_size,
                              hipStream_t stream)
{
    const float* Q    = (const float*)d_in[0];
    const float* K    = (const float*)d_in[1];
    const float* V    = (const float*)d_in[2];
    const int*   mask = (const int*)d_in[3];
    const float* Wq   = (const float*)d_in[4];
    const float* bq   = (const float*)d_in[5];
    const float* Wk   = (const float*)d_in[6];
    const float* bk   = (const float*)d_in[7];
    const float* Wv   = (const float*)d_in[8];
    const float* bv   = (const float*)d_in[9];
    const float* Wo   = (const float*)d_in[10];
    const float* bo   = (const float*)d_in[11];
    float* out = (float*)d_out;

    // ws (48 MB): Wcat 8 + Qf 8 + Kf 8 + Vt 8 + Xr 8 + Qb 8.
    // Aliases: Kb = Xr (dead before attn writes), Vb = d_out (first 8 MB,
    // dead before gemm_out writes), maskb = d_out second half (16 KB; attn
    // reads it before gemm_out overwrites d_out — stream-ordered).
    ushort_t* Wqb = (ushort_t*)d_ws;
    ushort_t* Wkb = Wqb + (1 << 20);
    ushort_t* Wvb = Wkb + (1 << 20);
    ushort_t* Wob = Wvb + (1 << 20);
    ushort_t* Qf  = Wob + (1 << 20);
    ushort_t* Kf  = Qf + (size_t)MROWS * DF;
    ushort_t* Vt  = Kf + (size_t)MROWS * DF;
    ushort_t* Xr  = Vt + (size_t)MROWS * DF;
    ushort_t* Qb  = Xr + (size_t)MROWS * DF;
    ushort_t* Kb  = Xr;
    ushort_t* Vb  = (ushort_t*)d_out;
    float*    maskb = (float*)((ushort_t*)d_out + (size_t)(1 << 22));  // +8 MB

    const int nin = MROWS * DF;  // 4M
    const int nw  = DF * DF;     // 1M

    CvtArgs ca;
    ca.src[0] = Q;  ca.dst[0] = Qb;  ca.n[0] = nin;
    ca.src[1] = K;  ca.dst[1] = Kb;  ca.n[1] = nin;
    ca.src[2] = V;  ca.dst[2] = Vb;  ca.n[2] = nin;
    ca.src[3] = Wq; ca.dst[3] = Wqb; ca.n[3] = nw;
    ca.src[4] = Wk; ca.dst[4] = Wkb; ca.n[4] = nw;
    ca.src[5] = Wv; ca.dst[5] = Wvb; ca.n[5] = nw;
    ca.src[6] = Wo; ca.dst[6] = Wob; ca.n[6] = nw;
    ca.msrc = mask;
    ca.mdst = maskb;

    dim3 blk(256);
    cvt_all<<<dim3(nin / 1024, 8), blk, 0, stream>>>(ca);

    gemm_qkv<<<dim3(24, 32), blk, 0, stream>>>(Qb, Kb, Vb, Wqb, bq, bk, bv,
                                               Qf, Kf, Vt);

    attn_mfma<<<dim3(SEQ / 64, NH, BATCH), blk, 0, stream>>>(Qf, Kf, Vt, maskb, Xr);

    gemm_out<<<dim3(16, 32), blk, 0, stream>>>(Xr, Wob, bo, out);
}

// Round 4
// 238.337 us; speedup vs baseline: 1.4322x; 1.4322x over previous
//
#include <hip/hip_runtime.h>

// MultiHeadedAttention B=2,S=2048,D=1024,H=16,Dh=64 — f32 in/out.
// Round 11 (= R9 structure + XCD co-location swizzle in attn):
//   - R10's direct-V reverted (global->reg V was 2.5x slower: compiler sinks
//     the loads to their PV use + 16x 64B-segment scatter per instr).
//   - attn grid is now 1-D (1024); decode hb = f & 31, q0 = (f>>5)*64.
//     XCD = dispatch%8 and 32%8==0, so all 32 q-blocks sharing one head's
//     K/V (512 KB) land on ONE XCD -> K/V L2-resident (4 heads = 2 MB/XCD),
//     killing the ~8x HBM re-fetch (FETCH 69.7 MB) and the ~900cy staging
//     latency that overflowed the compute body at every barrier.
// R9: K/V LDS double-buffered, one __syncthreads/iter, mask loads issued
// before staging (vmcnt retires in order). R8: exp2-direct softmax (scale
// log2e/32 folded into Q), additive mask-bias plane, v_cvt_pk_bf16_f32 pack.
// MFMA frag layouts + XOR-slot swizzle hardware-verified (rounds 3-6).

typedef unsigned short ushort_t;
typedef __attribute__((ext_vector_type(8))) short short8;
typedef __attribute__((ext_vector_type(4))) float floatx4;

#define BATCH 2
#define SEQ   2048
#define DF    1024
#define NH    16
#define DH    64
#define MROWS 4096

__device__ __forceinline__ float bf2f(ushort_t u) {
    return __uint_as_float(((unsigned int)u) << 16);
}
__device__ __forceinline__ ushort_t f2bf(float f) {
    unsigned int u = __float_as_uint(f);
    u += 0x7FFFu + ((u >> 16) & 1u);   // RNE
    return (ushort_t)(u >> 16);
}

__device__ __forceinline__ float exp2_fast(float x) {
#if defined(__has_builtin)
#if __has_builtin(__builtin_amdgcn_exp2f)
    return __builtin_amdgcn_exp2f(x);
#else
    float r; asm("v_exp_f32 %0, %1" : "=v"(r) : "v"(x)); return r;
#endif
#else
    float r; asm("v_exp_f32 %0, %1" : "=v"(r) : "v"(x)); return r;
#endif
}

// ---------------------------------------------------------------------------
// Fused f32->bf16 conversion of 7 tensors + int-mask -> float-bias plane.
// ---------------------------------------------------------------------------
struct CvtArgs {
    const float* src[7];
    ushort_t*    dst[7];
    int          n[7];
    const int*   msrc;   // int mask  [B*S]
    float*       mdst;   // float bias [B*S]: mask? 0 : -1e9
};

__global__ __launch_bounds__(256) void cvt_all(CvtArgs a)
{
    const int y = blockIdx.y;
    if (y == 7) {
        int i = (blockIdx.x * 256 + threadIdx.x) * 4;
        if (i >= BATCH * SEQ) return;
        int4 m = *(const int4*)(a.msrc + i);
        float4 o;
        o.x = m.x ? 0.f : -1e9f;
        o.y = m.y ? 0.f : -1e9f;
        o.z = m.z ? 0.f : -1e9f;
        o.w = m.w ? 0.f : -1e9f;
        *(float4*)(a.mdst + i) = o;
        return;
    }
    const int n = a.n[y];
    int i = (blockIdx.x * 256 + threadIdx.x) * 4;
    if (i >= n) return;
    const float* in = a.src[y];
    ushort_t* out = a.dst[y];
    float4 v = *(const float4*)(in + i);
    ushort4 o;
    o.x = f2bf(v.x); o.y = f2bf(v.y); o.z = f2bf(v.z); o.w = f2bf(v.w);
    *(ushort4*)(out + i) = o;
}

// ---------------------------------------------------------------------------
// Fused QKV projections, all-bf16 operands. Grid (24,32): n0 = bx*128.
//   n0 <1024: Qf (A=Qb, bq, epilogue scale log2e/32 — folds softmax scale AND
//             the exp->exp2 conversion)
//   <2048:    Kf (A=Kb, bk)
//   else:     Vt DIRECT (A=Vb, bv) — transposed write [(b*16+h)*64+dh][s],
//             thread's 4 acc regs per (mt,nt) are 4 consecutive s -> ushort4.
// 128x128 tile, BK=64, global_load_lds staging, XOR-slot swizzle (verified).
// ---------------------------------------------------------------------------
__global__ __launch_bounds__(256) void gemm_qkv(
    const ushort_t* __restrict__ Qb, const ushort_t* __restrict__ Kb,
    const ushort_t* __restrict__ Vb, const ushort_t* __restrict__ Wcat,
    const float* __restrict__ bq, const float* __restrict__ bk,
    const float* __restrict__ bv,
    ushort_t* __restrict__ Qf, ushort_t* __restrict__ Kf,
    ushort_t* __restrict__ Vt)
{
    __shared__ ushort_t As[128 * 64];  // 16 KB, [row][slot], slot = k8 ^ (row&7)
    __shared__ ushort_t Bs[128 * 64];  // 16 KB

    const int t = threadIdx.x;
    const int lane = t & 63, w = t >> 6;
    const int x = lane & 15, y = lane >> 4;
    const int wm = (w >> 1) * 64, wn = (w & 1) * 64;
    const int m0 = blockIdx.y << 7, n0 = blockIdx.x << 7;

    const ushort_t* Ab; const float* bp;
    if (n0 < 1024)      { Ab = Qb; bp = bq; }
    else if (n0 < 2048) { Ab = Kb; bp = bk; }
    else                { Ab = Vb; bp = bv; }
    const int ncol0 = n0 & 1023;

    floatx4 acc[4][4] = {};

    for (int kt = 0; kt < 16; ++kt) {
        const int k0 = kt * 64;

        #pragma unroll
        for (int j = 0; j < 4; ++j) {   // A stage
            int i   = (w << 2) + j;
            int c   = (i << 6) + lane;
            int row = c >> 3;
            int s   = c & 7;
            int k8  = s ^ (row & 7);
            const ushort_t* g = Ab + (size_t)(m0 + row) * DF + k0 + (k8 << 3);
            __builtin_amdgcn_global_load_lds(
                (const __attribute__((address_space(1))) unsigned int*)g,
                (__attribute__((address_space(3))) unsigned int*)(As + (i << 9)),
                16, 0, 0);
        }
        #pragma unroll
        for (int j = 0; j < 4; ++j) {   // B stage
            int i   = (w << 2) + j;
            int c   = (i << 6) + lane;
            int row = c >> 3;
            int s   = c & 7;
            int k8  = s ^ (row & 7);
            const ushort_t* g = Wcat + (size_t)(n0 + row) * DF + k0 + (k8 << 3);
            __builtin_amdgcn_global_load_lds(
                (const __attribute__((address_space(1))) unsigned int*)g,
                (__attribute__((address_space(3))) unsigned int*)(Bs + (i << 9)),
                16, 0, 0);
        }
        __syncthreads();

        #pragma unroll
        for (int kh = 0; kh < 2; ++kh) {
            const int slot = ((kh << 2) + y) ^ (x & 7);
            short8 af[4], bfr[4];
            #pragma unroll
            for (int mt = 0; mt < 4; ++mt)
                af[mt] = *(const short8*)(As + (wm + (mt << 4) + x) * 64 + slot * 8);
            #pragma unroll
            for (int nt = 0; nt < 4; ++nt)
                bfr[nt] = *(const short8*)(Bs + (wn + (nt << 4) + x) * 64 + slot * 8);
            #pragma unroll
            for (int mt = 0; mt < 4; ++mt)
                #pragma unroll
                for (int nt = 0; nt < 4; ++nt)
                    acc[mt][nt] = __builtin_amdgcn_mfma_f32_16x16x32_bf16(
                        af[mt], bfr[nt], acc[mt][nt], 0, 0, 0);
        }
        __syncthreads();
    }

    float bvv[4];
    #pragma unroll
    for (int nt = 0; nt < 4; ++nt) bvv[nt] = bp[ncol0 + wn + (nt << 4) + x];

    if (n0 < 2048) {
        // Qf/Kf: natural layout, scale log2e/32 for Q (softmax scale + exp2 fold)
        ushort_t* outp = (n0 < 1024) ? Qf : Kf;
        const float osc = (n0 < 1024) ? 0.0450842200f : 1.0f;  // log2(e)/32
        #pragma unroll
        for (int mt = 0; mt < 4; ++mt) {
            #pragma unroll
            for (int r = 0; r < 4; ++r) {
                const size_t grow = (size_t)(m0 + wm + (mt << 4) + (y << 2) + r) * DF;
                #pragma unroll
                for (int nt = 0; nt < 4; ++nt)
                    outp[grow + ncol0 + wn + (nt << 4) + x] =
                        f2bf((acc[mt][nt][r] + bvv[nt]) * osc);
            }
        }
    } else {
        // V: direct transposed write to Vt[(b*16+h)*64+dh][s]
        #pragma unroll
        for (int mt = 0; mt < 4; ++mt) {
            int m   = m0 + wm + (mt << 4) + (y << 2);  // +r are consecutive s
            int bb2 = m >> 11;
            int s0  = m & 2047;
            #pragma unroll
            for (int nt = 0; nt < 4; ++nt) {
                int col = ncol0 + wn + (nt << 4) + x;  // h*64+dh
                ushort4 pk;
                pk.x = f2bf(acc[mt][nt][0] + bvv[nt]);
                pk.y = f2bf(acc[mt][nt][1] + bvv[nt]);
                pk.z = f2bf(acc[mt][nt][2] + bvv[nt]);
                pk.w = f2bf(acc[mt][nt][3] + bvv[nt]);
                *(ushort4*)(Vt + ((size_t)(bb2 << 10) + col) * 2048 + s0) = pk;
            }
        }
    }
}

// ---------------------------------------------------------------------------
// Out-projection: C[4096,1024] = Xr @ Wo^T + bo, f32 out.
// Tile 128(M) x 64(N), grid (16,32) = 512 blocks = 2/CU. Wave-tile 64x32.
// ---------------------------------------------------------------------------
__global__ __launch_bounds__(256) void gemm_out(
    const ushort_t* __restrict__ Xr, const ushort_t* __restrict__ Wb,
    const float* __restrict__ bias, float* __restrict__ C)
{
    __shared__ ushort_t As[128 * 64];  // 16 KB
    __shared__ ushort_t Bs[64 * 64];   // 8 KB

    const int t = threadIdx.x;
    const int lane = t & 63, w = t >> 6;
    const int x = lane & 15, y = lane >> 4;
    const int wm = (w >> 1) * 64, wn = (w & 1) * 32;
    const int m0 = blockIdx.y << 7, n0 = blockIdx.x << 6;

    floatx4 acc[4][2] = {};

    for (int kt = 0; kt < 16; ++kt) {
        const int k0 = kt * 64;

        #pragma unroll
        for (int j = 0; j < 4; ++j) {   // A stage: 16 KB
            int i   = (w << 2) + j;
            int c   = (i << 6) + lane;
            int row = c >> 3;
            int s   = c & 7;
            int k8  = s ^ (row & 7);
            const ushort_t* g = Xr + (size_t)(m0 + row) * DF + k0 + (k8 << 3);
            __builtin_amdgcn_global_load_lds(
                (const __attribute__((address_space(1))) unsigned int*)g,
                (__attribute__((address_space(3))) unsigned int*)(As + (i << 9)),
                16, 0, 0);
        }
        #pragma unroll
        for (int j = 0; j < 2; ++j) {   // B stage: 8 KB
            int i   = (w << 1) + j;
            int c   = (i << 6) + lane;
            int row = c >> 3;
            int s   = c & 7;
            int k8  = s ^ (row & 7);
            const ushort_t* g = Wb + (size_t)(n0 + row) * DF + k0 + (k8 << 3);
            __builtin_amdgcn_global_load_lds(
                (const __attribute__((address_space(1))) unsigned int*)g,
                (__attribute__((address_space(3))) unsigned int*)(Bs + (i << 9)),
                16, 0, 0);
        }
        __syncthreads();

        #pragma unroll
        for (int kh = 0; kh < 2; ++kh) {
            const int slot = ((kh << 2) + y) ^ (x & 7);
            short8 af[4], bfr[2];
            #pragma unroll
            for (int mt = 0; mt < 4; ++mt)
                af[mt] = *(const short8*)(As + (wm + (mt << 4) + x) * 64 + slot * 8);
            #pragma unroll
            for (int nt = 0; nt < 2; ++nt)
                bfr[nt] = *(const short8*)(Bs + (wn + (nt << 4) + x) * 64 + slot * 8);
            #pragma unroll
            for (int mt = 0; mt < 4; ++mt)
                #pragma unroll
                for (int nt = 0; nt < 2; ++nt)
                    acc[mt][nt] = __builtin_amdgcn_mfma_f32_16x16x32_bf16(
                        af[mt], bfr[nt], acc[mt][nt], 0, 0, 0);
        }
        __syncthreads();
    }

    float bvv[2];
    #pragma unroll
    for (int nt = 0; nt < 2; ++nt) bvv[nt] = bias[n0 + wn + (nt << 4) + x];

    #pragma unroll
    for (int mt = 0; mt < 4; ++mt) {
        #pragma unroll
        for (int r = 0; r < 4; ++r) {
            const size_t grow = (size_t)(m0 + wm + (mt << 4) + (y << 2) + r) * DF;
            #pragma unroll
            for (int nt = 0; nt < 2; ++nt)
                C[grow + n0 + wn + (nt << 4) + x] = acc[mt][nt][r] + bvv[nt];
        }
    }
}

// ---------------------------------------------------------------------------
// Attention, full MFMA, S^T variant, double-buffered K/V staging.
// QK^T swapped: sacc[mt] = mfma(kfrag, qfrag) -> D[row=key][col=q]; thread
// (x,y) owns keys mt*16+y*4..+3 for q=wm+x. Softmax: additive float bias,
// raw v_exp_f32 (scale folded into Q), P packed via v_cvt_pk_bf16_f32 ->
// ds_write_b64. P region wave-local -> no mid barrier.
//
// Grid: 1-D, 1024 blocks. f = blockIdx.x; hb = f & 31 (b*16+h); q0 =
// (f>>5)*64. Dispatch XCD = f%8 and 32%8==0 => all 32 q-blocks of one head
// stay on one XCD; 4 heads/XCD = 2 MB K/V, L2-resident staging.
//
// Pipeline: stage(kt+1 -> buf^1) issued at top of iter kt; compute tile kt
// from buf; ONE __syncthreads at iteration end. Mask loads issued BEFORE
// stage loads (vmcnt retires in order -> softmax waits at vmcnt(4)).
// LDS 40 KB (4 blocks/CU, same as grid supplies).
// ---------------------------------------------------------------------------
__global__ __launch_bounds__(256) void attn_mfma(
    const ushort_t* __restrict__ Qf, const ushort_t* __restrict__ Kf,
    const ushort_t* __restrict__ Vt, const float* __restrict__ maskb,
    ushort_t* __restrict__ Xr)
{
    __shared__ ushort_t Qs[64 * 64];      // 8 KB; becomes Ps after qfrag extract
    __shared__ ushort_t Ks[2][64 * 64];   // 16 KB double-buffered
    __shared__ ushort_t Vs[2][64 * 64];   // 16 KB double-buffered
    ushort_t* Ps = Qs;

    const int t = threadIdx.x;
    const int lane = t & 63, w = t >> 6;
    const int x = lane & 15, y = lane >> 4;
    const int wm = w << 4;

    // XCD co-location decode: hb in low 5 bits -> XCD = f%8 = hb%8 fixed
    // across a head's 32 q-blocks.
    const int f  = blockIdx.x;
    const int hb = f & 31;          // b*16 + h
    const int b  = hb >> 4;
    const int h  = hb & 15;
    const int q0 = (f >> 5) << 6;

    const size_t qkbase = ((size_t)b * SEQ) * DF + (size_t)h * DH;
    const size_t vbase  = ((size_t)(b * NH + h) * DH) * SEQ;
    const int mbase = b * SEQ;

    // Staging geometry (per wave: 4 of the 16 tile-rows-of-8):
    const int i_s  = (w << 2);            // first i for K/V stage
    const int c0   = lane;                // column part reused every iter

    // ---- prologue: Q stage + K/V tile 0 into buf 0 ----
    #pragma unroll
    for (int j = 0; j < 2; ++j) {
        int i   = (w << 1) + j;
        int c   = (i << 6) + lane;
        int row = c >> 3;
        int s   = c & 7;
        int k8  = s ^ (row & 7);
        const ushort_t* g = Qf + qkbase + (size_t)(q0 + row) * DF + (k8 << 3);
        __builtin_amdgcn_global_load_lds(
            (const __attribute__((address_space(1))) unsigned int*)g,
            (__attribute__((address_space(3))) unsigned int*)(Qs + (i << 9)),
            16, 0, 0);
    }
    #pragma unroll
    for (int j = 0; j < 4; ++j) {
        int i   = i_s + j;
        int c   = (i << 6) + c0;
        int row = (c >> 3) & 63;
        int s   = c & 7;
        int k8  = s ^ (row & 7);
        if (i < 8) {
            const ushort_t* g = Kf + qkbase + (size_t)row * DF + (k8 << 3);
            __builtin_amdgcn_global_load_lds(
                (const __attribute__((address_space(1))) unsigned int*)g,
                (__attribute__((address_space(3))) unsigned int*)(Ks[0] + (i << 9)),
                16, 0, 0);
        } else {
            const ushort_t* g = Vt + vbase + (size_t)row * SEQ + (k8 << 3);
            __builtin_amdgcn_global_load_lds(
                (const __attribute__((address_space(1))) unsigned int*)g,
                (__attribute__((address_space(3))) unsigned int*)(Vs[0] + ((i - 8) << 9)),
                16, 0, 0);
        }
    }
    __syncthreads();

    short8 qfrag[2];
    #pragma unroll
    for (int kh = 0; kh < 2; ++kh) {
        int slot = ((kh << 2) + y) ^ (x & 7);
        qfrag[kh] = *(const short8*)(Qs + (wm + x) * 64 + slot * 8);
    }
    // qfrag ds_reads complete before the first QK^T MFMA (compiler lgkmcnt
    // wait), which precedes the first Ps write in program order; same-wave
    // DS ops complete in order -> no barrier needed before Ps reuse.

    floatx4 oacc[4] = {};
    float dsum = 0.f;

    for (int kt = 0; kt < 32; ++kt) {
        const int cur = kt & 1;
        const int k0 = kt << 6;

        // ---- mask-bias loads for THIS tile (issued first: vmcnt order) ----
        float4 mb[4];
        #pragma unroll
        for (int mt = 0; mt < 4; ++mt)
            mb[mt] = *(const float4*)(maskb + mbase + k0 + (mt << 4) + (y << 2));

        // ---- stage NEXT tile into the other buffer ----
        if (kt < 31) {
            const int k0n = (kt + 1) << 6;
            ushort_t* Kd = Ks[cur ^ 1];
            ushort_t* Vd = Vs[cur ^ 1];
            #pragma unroll
            for (int j = 0; j < 4; ++j) {
                int i   = i_s + j;
                int c   = (i << 6) + c0;
                int row = (c >> 3) & 63;
                int s   = c & 7;
                int k8  = s ^ (row & 7);
                if (i < 8) {
                    const ushort_t* g = Kf + qkbase + (size_t)(k0n + row) * DF + (k8 << 3);
                    __builtin_amdgcn_global_load_lds(
                        (const __attribute__((address_space(1))) unsigned int*)g,
                        (__attribute__((address_space(3))) unsigned int*)(Kd + (i << 9)),
                        16, 0, 0);
                } else {
                    const ushort_t* g = Vt + vbase + (size_t)row * SEQ + k0n + (k8 << 3);
                    __builtin_amdgcn_global_load_lds(
                        (const __attribute__((address_space(1))) unsigned int*)g,
                        (__attribute__((address_space(3))) unsigned int*)(Vd + ((i - 8) << 9)),
                        16, 0, 0);
                }
            }
        }

        // ---- S^T = K·Q^T on buf[cur]: D[row=key][col=q] ----
        const ushort_t* Kc = Ks[cur];
        const ushort_t* Vc = Vs[cur];
        floatx4 sacc[4] = {};
        #pragma unroll
        for (int kh = 0; kh < 2; ++kh) {
            const int slot = ((kh << 2) + y) ^ (x & 7);
            #pragma unroll
            for (int mt = 0; mt < 4; ++mt) {
                short8 kf = *(const short8*)(Kc + ((mt << 4) + x) * 64 + slot * 8);
                sacc[mt] = __builtin_amdgcn_mfma_f32_16x16x32_bf16(
                    kf, qfrag[kh], sacc[mt], 0, 0, 0);
            }
        }

        // ---- softmax: bias-add + exp2 + packed P write (wave-local rows) ----
        #pragma unroll
        for (int mt = 0; mt < 4; ++mt) {
            float p0 = exp2_fast(sacc[mt][0] + mb[mt].x);
            float p1 = exp2_fast(sacc[mt][1] + mb[mt].y);
            float p2 = exp2_fast(sacc[mt][2] + mb[mt].z);
            float p3 = exp2_fast(sacc[mt][3] + mb[mt].w);
            dsum += (p0 + p1) + (p2 + p3);
            unsigned int w0, w1;
            asm("v_cvt_pk_bf16_f32 %0, %1, %2" : "=v"(w0) : "v"(p0), "v"(p1));
            asm("v_cvt_pk_bf16_f32 %0, %1, %2" : "=v"(w1) : "v"(p2), "v"(p3));
            uint2 pk; pk.x = w0; pk.y = w1;
            int slot2 = ((mt << 1) + (y >> 1)) ^ (x & 7);
            *(uint2*)(Ps + ((wm + x) << 6) + (slot2 << 3) + ((y & 1) << 2)) = pk;
        }

        // ---- PV: O strip 16q x 64dh (reads own wave's P rows) ----
        #pragma unroll
        for (int kh = 0; kh < 2; ++kh) {
            const int slot = ((kh << 2) + y) ^ (x & 7);
            short8 pf = *(const short8*)(Ps + (wm + x) * 64 + slot * 8);
            #pragma unroll
            for (int nt = 0; nt < 4; ++nt) {
                short8 vf = *(const short8*)(Vc + ((nt << 4) + x) * 64 + slot * 8);
                oacc[nt] = __builtin_amdgcn_mfma_f32_16x16x32_bf16(
                    pf, vf, oacc[nt], 0, 0, 0);
            }
        }

        __syncthreads();   // tile kt+1 staged & visible; buf[cur] reads drained
    }

    // dsum: thread holds partial for q=wm+x (keys y*4+r per tile);
    // reduce across the 4 y-lanes sharing x, then broadcast per output row.
    dsum += __shfl_xor(dsum, 16, 64);
    dsum += __shfl_xor(dsum, 32, 64);
    float rdv[4];
    #pragma unroll
    for (int r = 0; r < 4; ++r)
        rdv[r] = 1.0f / __shfl(dsum, (y << 2) + r, 64);

    #pragma unroll
    for (int r = 0; r < 4; ++r) {
        int q = q0 + wm + (y << 2) + r;
        #pragma unroll
        for (int nt = 0; nt < 4; ++nt)
            Xr[qkbase + (size_t)q * DF + (nt << 4) + x] = f2bf(oacc[nt][r] * rdv[r]);
    }
}

// ---------------------------------------------------------------------------
extern "C" void kernel_launch(void* const* d_in, const int* in_sizes, int n_in,
                              void* d_out, int out_size, void* d_ws, size_t ws_size,
                              hipStream_t stream)
{
    const float* Q    = (const float*)d_in[0];
    const float* K    = (const float*)d_in[1];
    const float* V    = (const float*)d_in[2];
    const int*   mask = (const int*)d_in[3];
    const float* Wq   = (const float*)d_in[4];
    const float* bq   = (const float*)d_in[5];
    const float* Wk   = (const float*)d_in[6];
    const float* bk   = (const float*)d_in[7];
    const float* Wv   = (const float*)d_in[8];
    const float* bv   = (const float*)d_in[9];
    const float* Wo   = (const float*)d_in[10];
    const float* bo   = (const float*)d_in[11];
    float* out = (float*)d_out;

    // ws (48 MB): Wcat 8 + Qf 8 + Kf 8 + Vt 8 + Xr 8 + Qb 8.
    // Aliases: Kb = Xr (dead before attn writes), Vb = d_out (first 8 MB,
    // dead before gemm_out writes), maskb = d_out second half (16 KB; attn
    // reads it before gemm_out overwrites d_out — stream-ordered).
    ushort_t* Wqb = (ushort_t*)d_ws;
    ushort_t* Wkb = Wqb + (1 << 20);
    ushort_t* Wvb = Wkb + (1 << 20);
    ushort_t* Wob = Wvb + (1 << 20);
    ushort_t* Qf  = Wob + (1 << 20);
    ushort_t* Kf  = Qf + (size_t)MROWS * DF;
    ushort_t* Vt  = Kf + (size_t)MROWS * DF;
    ushort_t* Xr  = Vt + (size_t)MROWS * DF;
    ushort_t* Qb  = Xr + (size_t)MROWS * DF;
    ushort_t* Kb  = Xr;
    ushort_t* Vb  = (ushort_t*)d_out;
    float*    maskb = (float*)((ushort_t*)d_out + (size_t)(1 << 22));  // +8 MB

    const int nin = MROWS * DF;  // 4M
    const int nw  = DF * DF;     // 1M

    CvtArgs ca;
    ca.src[0] = Q;  ca.dst[0] = Qb;  ca.n[0] = nin;
    ca.src[1] = K;  ca.dst[1] = Kb;  ca.n[1] = nin;
    ca.src[2] = V;  ca.dst[2] = Vb;  ca.n[2] = nin;
    ca.src[3] = Wq; ca.dst[3] = Wqb; ca.n[3] = nw;
    ca.src[4] = Wk; ca.dst[4] = Wkb; ca.n[4] = nw;
    ca.src[5] = Wv; ca.dst[5] = Wvb; ca.n[5] = nw;
    ca.src[6] = Wo; ca.dst[6] = Wob; ca.n[6] = nw;
    ca.msrc = mask;
    ca.mdst = maskb;

    dim3 blk(256);
    cvt_all<<<dim3(nin / 1024, 8), blk, 0, stream>>>(ca);

    gemm_qkv<<<dim3(24, 32), blk, 0, stream>>>(Qb, Kb, Vb, Wqb, bq, bk, bv,
                                               Qf, Kf, Vt);

    attn_mfma<<<dim3(1024), blk, 0, stream>>>(Qf, Kf, Vt, maskb, Xr);

    gemm_out<<<dim3(16, 32), blk, 0, stream>>>(Xr, Wob, bo, out);
}

// Round 5
// 234.744 us; speedup vs baseline: 1.4541x; 1.0153x over previous
//
#include <hip/hip_runtime.h>

// MultiHeadedAttention B=2,S=2048,D=1024,H=16,Dh=64 — f32 in/out.
// Round 12:
//   - attn: s_setprio(1) around QK^T and PV MFMA clusters (T5; waves from 4
//     independent blocks per SIMD give the role diversity T5 needs);
//     dsum split into 4 independent accumulators (no -ffast-math, so the
//     compiler can't reassociate the 128-add serial chain itself).
//   - gemm_qkv / gemm_out: XCD-chunked 1-D grids. Old mapping spread the 8
//     blocks sharing an A-panel across all 8 XCDs (same L2 re-fetch disease
//     attn had pre-R11). New decode: xcd = f&7 owns by ∈ [4*xcd, 4*xcd+4)
//     × all n-blocks; bijective. gemm_out per-XCD set (1MB A + 2MB B) fits
//     the 4MB L2 outright.
// R11: attn 1-D grid, head's 32 q-blocks co-located per XCD (FETCH 69.7->12.4
// MB verified). R9: K/V LDS dbuf, one barrier/iter. R8: exp2-direct softmax,
// additive mask-bias plane, v_cvt_pk_bf16_f32 pack.
// MFMA frag layouts + XOR-slot swizzle hardware-verified (rounds 3-6).

typedef unsigned short ushort_t;
typedef __attribute__((ext_vector_type(8))) short short8;
typedef __attribute__((ext_vector_type(4))) float floatx4;

#define BATCH 2
#define SEQ   2048
#define DF    1024
#define NH    16
#define DH    64
#define MROWS 4096

__device__ __forceinline__ float bf2f(ushort_t u) {
    return __uint_as_float(((unsigned int)u) << 16);
}
__device__ __forceinline__ ushort_t f2bf(float f) {
    unsigned int u = __float_as_uint(f);
    u += 0x7FFFu + ((u >> 16) & 1u);   // RNE
    return (ushort_t)(u >> 16);
}

__device__ __forceinline__ float exp2_fast(float x) {
#if defined(__has_builtin)
#if __has_builtin(__builtin_amdgcn_exp2f)
    return __builtin_amdgcn_exp2f(x);
#else
    float r; asm("v_exp_f32 %0, %1" : "=v"(r) : "v"(x)); return r;
#endif
#else
    float r; asm("v_exp_f32 %0, %1" : "=v"(r) : "v"(x)); return r;
#endif
}

// ---------------------------------------------------------------------------
// Fused f32->bf16 conversion of 7 tensors + int-mask -> float-bias plane.
// ---------------------------------------------------------------------------
struct CvtArgs {
    const float* src[7];
    ushort_t*    dst[7];
    int          n[7];
    const int*   msrc;   // int mask  [B*S]
    float*       mdst;   // float bias [B*S]: mask? 0 : -1e9
};

__global__ __launch_bounds__(256) void cvt_all(CvtArgs a)
{
    const int y = blockIdx.y;
    if (y == 7) {
        int i = (blockIdx.x * 256 + threadIdx.x) * 4;
        if (i >= BATCH * SEQ) return;
        int4 m = *(const int4*)(a.msrc + i);
        float4 o;
        o.x = m.x ? 0.f : -1e9f;
        o.y = m.y ? 0.f : -1e9f;
        o.z = m.z ? 0.f : -1e9f;
        o.w = m.w ? 0.f : -1e9f;
        *(float4*)(a.mdst + i) = o;
        return;
    }
    const int n = a.n[y];
    int i = (blockIdx.x * 256 + threadIdx.x) * 4;
    if (i >= n) return;
    const float* in = a.src[y];
    ushort_t* out = a.dst[y];
    float4 v = *(const float4*)(in + i);
    ushort4 o;
    o.x = f2bf(v.x); o.y = f2bf(v.y); o.z = f2bf(v.z); o.w = f2bf(v.w);
    *(ushort4*)(out + i) = o;
}

// ---------------------------------------------------------------------------
// Fused QKV projections, all-bf16 operands. 1-D grid 768, XCD-chunked:
//   xcd = f&7 owns by ∈ [4*xcd, 4*xcd+4) x all 24 n-blocks -> each A-panel
//   (Qb/Kb/Vb 128-row stripe) is fetched by ONE XCD's L2.
//   n0 <1024: Qf (A=Qb, bq, epilogue scale log2e/32)
//   <2048:    Kf (A=Kb, bk)
//   else:     Vt DIRECT (A=Vb, bv) — transposed write [(b*16+h)*64+dh][s].
// 128x128 tile, BK=64, global_load_lds staging, XOR-slot swizzle (verified).
// ---------------------------------------------------------------------------
__global__ __launch_bounds__(256) void gemm_qkv(
    const ushort_t* __restrict__ Qb, const ushort_t* __restrict__ Kb,
    const ushort_t* __restrict__ Vb, const ushort_t* __restrict__ Wcat,
    const float* __restrict__ bq, const float* __restrict__ bk,
    const float* __restrict__ bv,
    ushort_t* __restrict__ Qf, ushort_t* __restrict__ Kf,
    ushort_t* __restrict__ Vt)
{
    __shared__ ushort_t As[128 * 64];  // 16 KB, [row][slot], slot = k8 ^ (row&7)
    __shared__ ushort_t Bs[128 * 64];  // 16 KB

    const int t = threadIdx.x;
    const int lane = t & 63, w = t >> 6;
    const int x = lane & 15, y = lane >> 4;
    const int wm = (w >> 1) * 64, wn = (w & 1) * 64;

    // XCD-chunked decode (bijective over 768): xcd owns 4 by-rows x 24 nb.
    const int f   = blockIdx.x;
    const int xcd = f & 7;
    const int idx = f >> 3;                     // 0..95
    const int m0  = (((xcd << 2) + (idx & 3)) << 7);
    const int n0  = (idx >> 2) << 7;            // 0..2944

    const ushort_t* Ab; const float* bp;
    if (n0 < 1024)      { Ab = Qb; bp = bq; }
    else if (n0 < 2048) { Ab = Kb; bp = bk; }
    else                { Ab = Vb; bp = bv; }
    const int ncol0 = n0 & 1023;

    floatx4 acc[4][4] = {};

    for (int kt = 0; kt < 16; ++kt) {
        const int k0 = kt * 64;

        #pragma unroll
        for (int j = 0; j < 4; ++j) {   // A stage
            int i   = (w << 2) + j;
            int c   = (i << 6) + lane;
            int row = c >> 3;
            int s   = c & 7;
            int k8  = s ^ (row & 7);
            const ushort_t* g = Ab + (size_t)(m0 + row) * DF + k0 + (k8 << 3);
            __builtin_amdgcn_global_load_lds(
                (const __attribute__((address_space(1))) unsigned int*)g,
                (__attribute__((address_space(3))) unsigned int*)(As + (i << 9)),
                16, 0, 0);
        }
        #pragma unroll
        for (int j = 0; j < 4; ++j) {   // B stage
            int i   = (w << 2) + j;
            int c   = (i << 6) + lane;
            int row = c >> 3;
            int s   = c & 7;
            int k8  = s ^ (row & 7);
            const ushort_t* g = Wcat + (size_t)(n0 + row) * DF + k0 + (k8 << 3);
            __builtin_amdgcn_global_load_lds(
                (const __attribute__((address_space(1))) unsigned int*)g,
                (__attribute__((address_space(3))) unsigned int*)(Bs + (i << 9)),
                16, 0, 0);
        }
        __syncthreads();

        #pragma unroll
        for (int kh = 0; kh < 2; ++kh) {
            const int slot = ((kh << 2) + y) ^ (x & 7);
            short8 af[4], bfr[4];
            #pragma unroll
            for (int mt = 0; mt < 4; ++mt)
                af[mt] = *(const short8*)(As + (wm + (mt << 4) + x) * 64 + slot * 8);
            #pragma unroll
            for (int nt = 0; nt < 4; ++nt)
                bfr[nt] = *(const short8*)(Bs + (wn + (nt << 4) + x) * 64 + slot * 8);
            __builtin_amdgcn_s_setprio(1);
            #pragma unroll
            for (int mt = 0; mt < 4; ++mt)
                #pragma unroll
                for (int nt = 0; nt < 4; ++nt)
                    acc[mt][nt] = __builtin_amdgcn_mfma_f32_16x16x32_bf16(
                        af[mt], bfr[nt], acc[mt][nt], 0, 0, 0);
            __builtin_amdgcn_s_setprio(0);
        }
        __syncthreads();
    }

    float bvv[4];
    #pragma unroll
    for (int nt = 0; nt < 4; ++nt) bvv[nt] = bp[ncol0 + wn + (nt << 4) + x];

    if (n0 < 2048) {
        // Qf/Kf: natural layout, scale log2e/32 for Q (softmax scale + exp2 fold)
        ushort_t* outp = (n0 < 1024) ? Qf : Kf;
        const float osc = (n0 < 1024) ? 0.0450842200f : 1.0f;  // log2(e)/32
        #pragma unroll
        for (int mt = 0; mt < 4; ++mt) {
            #pragma unroll
            for (int r = 0; r < 4; ++r) {
                const size_t grow = (size_t)(m0 + wm + (mt << 4) + (y << 2) + r) * DF;
                #pragma unroll
                for (int nt = 0; nt < 4; ++nt)
                    outp[grow + ncol0 + wn + (nt << 4) + x] =
                        f2bf((acc[mt][nt][r] + bvv[nt]) * osc);
            }
        }
    } else {
        // V: direct transposed write to Vt[(b*16+h)*64+dh][s]
        #pragma unroll
        for (int mt = 0; mt < 4; ++mt) {
            int m   = m0 + wm + (mt << 4) + (y << 2);  // +r are consecutive s
            int bb2 = m >> 11;
            int s0  = m & 2047;
            #pragma unroll
            for (int nt = 0; nt < 4; ++nt) {
                int col = ncol0 + wn + (nt << 4) + x;  // h*64+dh
                ushort4 pk;
                pk.x = f2bf(acc[mt][nt][0] + bvv[nt]);
                pk.y = f2bf(acc[mt][nt][1] + bvv[nt]);
                pk.z = f2bf(acc[mt][nt][2] + bvv[nt]);
                pk.w = f2bf(acc[mt][nt][3] + bvv[nt]);
                *(ushort4*)(Vt + ((size_t)(bb2 << 10) + col) * 2048 + s0) = pk;
            }
        }
    }
}

// ---------------------------------------------------------------------------
// Out-projection: C[4096,1024] = Xr @ Wo^T + bo, f32 out.
// 1-D grid 512, XCD-chunked: xcd = f&7 owns by ∈ [4*xcd,4*xcd+4) x 16 nb.
// Per-XCD set: 4 Xr panels (1MB) + full Wob (2MB) = 3MB < 4MB L2.
// Tile 128(M) x 64(N). Wave-tile 64x32.
// ---------------------------------------------------------------------------
__global__ __launch_bounds__(256) void gemm_out(
    const ushort_t* __restrict__ Xr, const ushort_t* __restrict__ Wb,
    const float* __restrict__ bias, float* __restrict__ C)
{
    __shared__ ushort_t As[128 * 64];  // 16 KB
    __shared__ ushort_t Bs[64 * 64];   // 8 KB

    const int t = threadIdx.x;
    const int lane = t & 63, w = t >> 6;
    const int x = lane & 15, y = lane >> 4;
    const int wm = (w >> 1) * 64, wn = (w & 1) * 32;

    const int f   = blockIdx.x;
    const int xcd = f & 7;
    const int idx = f >> 3;                    // 0..63
    const int m0  = (((xcd << 2) + (idx & 3)) << 7);
    const int n0  = (idx >> 2) << 6;           // 0..960

    floatx4 acc[4][2] = {};

    for (int kt = 0; kt < 16; ++kt) {
        const int k0 = kt * 64;

        #pragma unroll
        for (int j = 0; j < 4; ++j) {   // A stage: 16 KB
            int i   = (w << 2) + j;
            int c   = (i << 6) + lane;
            int row = c >> 3;
            int s   = c & 7;
            int k8  = s ^ (row & 7);
            const ushort_t* g = Xr + (size_t)(m0 + row) * DF + k0 + (k8 << 3);
            __builtin_amdgcn_global_load_lds(
                (const __attribute__((address_space(1))) unsigned int*)g,
                (__attribute__((address_space(3))) unsigned int*)(As + (i << 9)),
                16, 0, 0);
        }
        #pragma unroll
        for (int j = 0; j < 2; ++j) {   // B stage: 8 KB
            int i   = (w << 1) + j;
            int c   = (i << 6) + lane;
            int row = c >> 3;
            int s   = c & 7;
            int k8  = s ^ (row & 7);
            const ushort_t* g = Wb + (size_t)(n0 + row) * DF + k0 + (k8 << 3);
            __builtin_amdgcn_global_load_lds(
                (const __attribute__((address_space(1))) unsigned int*)g,
                (__attribute__((address_space(3))) unsigned int*)(Bs + (i << 9)),
                16, 0, 0);
        }
        __syncthreads();

        #pragma unroll
        for (int kh = 0; kh < 2; ++kh) {
            const int slot = ((kh << 2) + y) ^ (x & 7);
            short8 af[4], bfr[2];
            #pragma unroll
            for (int mt = 0; mt < 4; ++mt)
                af[mt] = *(const short8*)(As + (wm + (mt << 4) + x) * 64 + slot * 8);
            #pragma unroll
            for (int nt = 0; nt < 2; ++nt)
                bfr[nt] = *(const short8*)(Bs + (wn + (nt << 4) + x) * 64 + slot * 8);
            __builtin_amdgcn_s_setprio(1);
            #pragma unroll
            for (int mt = 0; mt < 4; ++mt)
                #pragma unroll
                for (int nt = 0; nt < 2; ++nt)
                    acc[mt][nt] = __builtin_amdgcn_mfma_f32_16x16x32_bf16(
                        af[mt], bfr[nt], acc[mt][nt], 0, 0, 0);
            __builtin_amdgcn_s_setprio(0);
        }
        __syncthreads();
    }

    float bvv[2];
    #pragma unroll
    for (int nt = 0; nt < 2; ++nt) bvv[nt] = bias[n0 + wn + (nt << 4) + x];

    #pragma unroll
    for (int mt = 0; mt < 4; ++mt) {
        #pragma unroll
        for (int r = 0; r < 4; ++r) {
            const size_t grow = (size_t)(m0 + wm + (mt << 4) + (y << 2) + r) * DF;
            #pragma unroll
            for (int nt = 0; nt < 2; ++nt)
                C[grow + n0 + wn + (nt << 4) + x] = acc[mt][nt][r] + bvv[nt];
        }
    }
}

// ---------------------------------------------------------------------------
// Attention, full MFMA, S^T variant, double-buffered K/V staging.
// QK^T swapped: sacc[mt] = mfma(kfrag, qfrag) -> D[row=key][col=q]; thread
// (x,y) owns keys mt*16+y*4..+3 for q=wm+x. Softmax: additive float bias,
// raw v_exp_f32 (scale folded into Q), P packed via v_cvt_pk_bf16_f32 ->
// ds_write_b64. P region wave-local -> no mid barrier.
//
// Grid: 1-D, 1024 blocks. f = blockIdx.x; hb = f & 31 (b*16+h); q0 =
// (f>>5)*64. XCD = f%8, 32%8==0 => all 32 q-blocks of one head on one XCD
// (verified R11: FETCH 69.7 -> 12.4 MB).
//
// R12: setprio(1) around both MFMA clusters (T5); dsum as 4 independent
// accumulators (breaks the serial FP-add chain; no -ffast-math).
// ---------------------------------------------------------------------------
__global__ __launch_bounds__(256) void attn_mfma(
    const ushort_t* __restrict__ Qf, const ushort_t* __restrict__ Kf,
    const ushort_t* __restrict__ Vt, const float* __restrict__ maskb,
    ushort_t* __restrict__ Xr)
{
    __shared__ ushort_t Qs[64 * 64];      // 8 KB; becomes Ps after qfrag extract
    __shared__ ushort_t Ks[2][64 * 64];   // 16 KB double-buffered
    __shared__ ushort_t Vs[2][64 * 64];   // 16 KB double-buffered
    ushort_t* Ps = Qs;

    const int t = threadIdx.x;
    const int lane = t & 63, w = t >> 6;
    const int x = lane & 15, y = lane >> 4;
    const int wm = w << 4;

    const int f  = blockIdx.x;
    const int hb = f & 31;          // b*16 + h
    const int b  = hb >> 4;
    const int h  = hb & 15;
    const int q0 = (f >> 5) << 6;

    const size_t qkbase = ((size_t)b * SEQ) * DF + (size_t)h * DH;
    const size_t vbase  = ((size_t)(b * NH + h) * DH) * SEQ;
    const int mbase = b * SEQ;

    const int i_s  = (w << 2);            // first i for K/V stage
    const int c0   = lane;

    // ---- prologue: Q stage + K/V tile 0 into buf 0 ----
    #pragma unroll
    for (int j = 0; j < 2; ++j) {
        int i   = (w << 1) + j;
        int c   = (i << 6) + lane;
        int row = c >> 3;
        int s   = c & 7;
        int k8  = s ^ (row & 7);
        const ushort_t* g = Qf + qkbase + (size_t)(q0 + row) * DF + (k8 << 3);
        __builtin_amdgcn_global_load_lds(
            (const __attribute__((address_space(1))) unsigned int*)g,
            (__attribute__((address_space(3))) unsigned int*)(Qs + (i << 9)),
            16, 0, 0);
    }
    #pragma unroll
    for (int j = 0; j < 4; ++j) {
        int i   = i_s + j;
        int c   = (i << 6) + c0;
        int row = (c >> 3) & 63;
        int s   = c & 7;
        int k8  = s ^ (row & 7);
        if (i < 8) {
            const ushort_t* g = Kf + qkbase + (size_t)row * DF + (k8 << 3);
            __builtin_amdgcn_global_load_lds(
                (const __attribute__((address_space(1))) unsigned int*)g,
                (__attribute__((address_space(3))) unsigned int*)(Ks[0] + (i << 9)),
                16, 0, 0);
        } else {
            const ushort_t* g = Vt + vbase + (size_t)row * SEQ + (k8 << 3);
            __builtin_amdgcn_global_load_lds(
                (const __attribute__((address_space(1))) unsigned int*)g,
                (__attribute__((address_space(3))) unsigned int*)(Vs[0] + ((i - 8) << 9)),
                16, 0, 0);
        }
    }
    __syncthreads();

    short8 qfrag[2];
    #pragma unroll
    for (int kh = 0; kh < 2; ++kh) {
        int slot = ((kh << 2) + y) ^ (x & 7);
        qfrag[kh] = *(const short8*)(Qs + (wm + x) * 64 + slot * 8);
    }

    floatx4 oacc[4] = {};
    float ds0 = 0.f, ds1 = 0.f, ds2 = 0.f, ds3 = 0.f;

    for (int kt = 0; kt < 32; ++kt) {
        const int cur = kt & 1;
        const int k0 = kt << 6;

        // ---- mask-bias loads for THIS tile (issued first: vmcnt order) ----
        float4 mb[4];
        #pragma unroll
        for (int mt = 0; mt < 4; ++mt)
            mb[mt] = *(const float4*)(maskb + mbase + k0 + (mt << 4) + (y << 2));

        // ---- stage NEXT tile into the other buffer ----
        if (kt < 31) {
            const int k0n = (kt + 1) << 6;
            ushort_t* Kd = Ks[cur ^ 1];
            ushort_t* Vd = Vs[cur ^ 1];
            #pragma unroll
            for (int j = 0; j < 4; ++j) {
                int i   = i_s + j;
                int c   = (i << 6) + c0;
                int row = (c >> 3) & 63;
                int s   = c & 7;
                int k8  = s ^ (row & 7);
                if (i < 8) {
                    const ushort_t* g = Kf + qkbase + (size_t)(k0n + row) * DF + (k8 << 3);
                    __builtin_amdgcn_global_load_lds(
                        (const __attribute__((address_space(1))) unsigned int*)g,
                        (__attribute__((address_space(3))) unsigned int*)(Kd + (i << 9)),
                        16, 0, 0);
                } else {
                    const ushort_t* g = Vt + vbase + (size_t)row * SEQ + k0n + (k8 << 3);
                    __builtin_amdgcn_global_load_lds(
                        (const __attribute__((address_space(1))) unsigned int*)g,
                        (__attribute__((address_space(3))) unsigned int*)(Vd + ((i - 8) << 9)),
                        16, 0, 0);
                }
            }
        }

        // ---- S^T = K·Q^T on buf[cur]: D[row=key][col=q] ----
        const ushort_t* Kc = Ks[cur];
        const ushort_t* Vc = Vs[cur];
        floatx4 sacc[4] = {};
        #pragma unroll
        for (int kh = 0; kh < 2; ++kh) {
            const int slot = ((kh << 2) + y) ^ (x & 7);
            short8 kf[4];
            #pragma unroll
            for (int mt = 0; mt < 4; ++mt)
                kf[mt] = *(const short8*)(Kc + ((mt << 4) + x) * 64 + slot * 8);
            __builtin_amdgcn_s_setprio(1);
            #pragma unroll
            for (int mt = 0; mt < 4; ++mt)
                sacc[mt] = __builtin_amdgcn_mfma_f32_16x16x32_bf16(
                    kf[mt], qfrag[kh], sacc[mt], 0, 0, 0);
            __builtin_amdgcn_s_setprio(0);
        }

        // ---- softmax: bias-add + exp2 + packed P write (wave-local rows) ----
        #pragma unroll
        for (int mt = 0; mt < 4; ++mt) {
            float p0 = exp2_fast(sacc[mt][0] + mb[mt].x);
            float p1 = exp2_fast(sacc[mt][1] + mb[mt].y);
            float p2 = exp2_fast(sacc[mt][2] + mb[mt].z);
            float p3 = exp2_fast(sacc[mt][3] + mb[mt].w);
            float pa = p0 + p1, pb = p2 + p3;
            if (mt == 0) ds0 += pa + pb;
            if (mt == 1) ds1 += pa + pb;
            if (mt == 2) ds2 += pa + pb;
            if (mt == 3) ds3 += pa + pb;
            unsigned int w0, w1;
            asm("v_cvt_pk_bf16_f32 %0, %1, %2" : "=v"(w0) : "v"(p0), "v"(p1));
            asm("v_cvt_pk_bf16_f32 %0, %1, %2" : "=v"(w1) : "v"(p2), "v"(p3));
            uint2 pk; pk.x = w0; pk.y = w1;
            int slot2 = ((mt << 1) + (y >> 1)) ^ (x & 7);
            *(uint2*)(Ps + ((wm + x) << 6) + (slot2 << 3) + ((y & 1) << 2)) = pk;
        }

        // ---- PV: O strip 16q x 64dh (reads own wave's P rows) ----
        #pragma unroll
        for (int kh = 0; kh < 2; ++kh) {
            const int slot = ((kh << 2) + y) ^ (x & 7);
            short8 pf = *(const short8*)(Ps + (wm + x) * 64 + slot * 8);
            short8 vf[4];
            #pragma unroll
            for (int nt = 0; nt < 4; ++nt)
                vf[nt] = *(const short8*)(Vc + ((nt << 4) + x) * 64 + slot * 8);
            __builtin_amdgcn_s_setprio(1);
            #pragma unroll
            for (int nt = 0; nt < 4; ++nt)
                oacc[nt] = __builtin_amdgcn_mfma_f32_16x16x32_bf16(
                    pf, vf[nt], oacc[nt], 0, 0, 0);
            __builtin_amdgcn_s_setprio(0);
        }

        __syncthreads();   // tile kt+1 staged & visible; buf[cur] reads drained
    }

    float dsum = (ds0 + ds1) + (ds2 + ds3);
    // reduce across the 4 y-lanes sharing x, then broadcast per output row.
    dsum += __shfl_xor(dsum, 16, 64);
    dsum += __shfl_xor(dsum, 32, 64);
    float rdv[4];
    #pragma unroll
    for (int r = 0; r < 4; ++r)
        rdv[r] = 1.0f / __shfl(dsum, (y << 2) + r, 64);

    #pragma unroll
    for (int r = 0; r < 4; ++r) {
        int q = q0 + wm + (y << 2) + r;
        #pragma unroll
        for (int nt = 0; nt < 4; ++nt)
            Xr[qkbase + (size_t)q * DF + (nt << 4) + x] = f2bf(oacc[nt][r] * rdv[r]);
    }
}

// ---------------------------------------------------------------------------
extern "C" void kernel_launch(void* const* d_in, const int* in_sizes, int n_in,
                              void* d_out, int out_size, void* d_ws, size_t ws_size,
                              hipStream_t stream)
{
    const float* Q    = (const float*)d_in[0];
    const float* K    = (const float*)d_in[1];
    const float* V    = (const float*)d_in[2];
    const int*   mask = (const int*)d_in[3];
    const float* Wq   = (const float*)d_in[4];
    const float* bq   = (const float*)d_in[5];
    const float* Wk   = (const float*)d_in[6];
    const float* bk   = (const float*)d_in[7];
    const float* Wv   = (const float*)d_in[8];
    const float* bv   = (const float*)d_in[9];
    const float* Wo   = (const float*)d_in[10];
    const float* bo   = (const float*)d_in[11];
    float* out = (float*)d_out;

    // ws (48 MB): Wcat 8 + Qf 8 + Kf 8 + Vt 8 + Xr 8 + Qb 8.
    // Aliases: Kb = Xr (dead before attn writes), Vb = d_out (first 8 MB,
    // dead before gemm_out writes), maskb = d_out second half (16 KB; attn
    // reads it before gemm_out overwrites d_out — stream-ordered).
    ushort_t* Wqb = (ushort_t*)d_ws;
    ushort_t* Wkb = Wqb + (1 << 20);
    ushort_t* Wvb = Wkb + (1 << 20);
    ushort_t* Wob = Wvb + (1 << 20);
    ushort_t* Qf  = Wob + (1 << 20);
    ushort_t* Kf  = Qf + (size_t)MROWS * DF;
    ushort_t* Vt  = Kf + (size_t)MROWS * DF;
    ushort_t* Xr  = Vt + (size_t)MROWS * DF;
    ushort_t* Qb  = Xr + (size_t)MROWS * DF;
    ushort_t* Kb  = Xr;
    ushort_t* Vb  = (ushort_t*)d_out;
    float*    maskb = (float*)((ushort_t*)d_out + (size_t)(1 << 22));  // +8 MB

    const int nin = MROWS * DF;  // 4M
    const int nw  = DF * DF;     // 1M

    CvtArgs ca;
    ca.src[0] = Q;  ca.dst[0] = Qb;  ca.n[0] = nin;
    ca.src[1] = K;  ca.dst[1] = Kb;  ca.n[1] = nin;
    ca.src[2] = V;  ca.dst[2] = Vb;  ca.n[2] = nin;
    ca.src[3] = Wq; ca.dst[3] = Wqb; ca.n[3] = nw;
    ca.src[4] = Wk; ca.dst[4] = Wkb; ca.n[4] = nw;
    ca.src[5] = Wv; ca.dst[5] = Wvb; ca.n[5] = nw;
    ca.src[6] = Wo; ca.dst[6] = Wob; ca.n[6] = nw;
    ca.msrc = mask;
    ca.mdst = maskb;

    dim3 blk(256);
    cvt_all<<<dim3(nin / 1024, 8), blk, 0, stream>>>(ca);

    gemm_qkv<<<dim3(768), blk, 0, stream>>>(Qb, Kb, Vb, Wqb, bq, bk, bv,
                                            Qf, Kf, Vt);

    attn_mfma<<<dim3(1024), blk, 0, stream>>>(Qf, Kf, Vt, maskb, Xr);

    gemm_out<<<dim3(512), blk, 0, stream>>>(Xr, Wob, bo, out);
}

// Round 6
// 231.889 us; speedup vs baseline: 1.4720x; 1.0123x over previous
//
#include <hip/hip_runtime.h>

// MultiHeadedAttention B=2,S=2048,D=1024,H=16,Dh=64 — f32 in/out.
// Round 13 (attn rebuilt on 32x32x16 MFMA, in-register P):
//   - Wave tile 32q x 64keys, block = 4 waves = 128 q. QK^T: D=S^T[key][q],
//     col=lane&31=q  -> each lane's 32 S values share ONE q.
//   - P never touches LDS: after exp2+cvt_pk, two v_permlane32_swap_b32 per
//     16-key chunk build the PV A-fragment in registers (T12 pattern).
//     DS ops/iter: 44 -> 16 (issue-bound kernel per R12 accounting).
//   - dsum: single shfl_xor(32) (lane pairs share q); rdv shared via dead Qs.
//   - setprio REMOVED from attn (R12: regressed 2.8us, lockstep structure).
// R12: GEMMs XCD-chunked 1-D grids (kept, +6.4us). R11: attn XCD co-location
// (FETCH 69.7->12.4 MB verified). R9: K/V dbuf, one barrier/iter. R8: exp2
// softmax (log2e/32 folded into Q), mask-bias plane, cvt_pk P-pack.
// 16x16 frag layouts + XOR-slot swizzle HW-verified (rounds 3-6); 32x32 C/D
// layout per guide (m74/m101): col=lane&31, row=(reg&3)+8*(reg>>2)+4*(lane>>5).

typedef unsigned short ushort_t;
typedef __attribute__((ext_vector_type(8)))  short short8;
typedef __attribute__((ext_vector_type(4)))  float floatx4;
typedef __attribute__((ext_vector_type(16))) float floatx16;

#define BATCH 2
#define SEQ   2048
#define DF    1024
#define NH    16
#define DH    64
#define MROWS 4096

__device__ __forceinline__ ushort_t f2bf(float f) {
    unsigned int u = __float_as_uint(f);
    u += 0x7FFFu + ((u >> 16) & 1u);   // RNE
    return (ushort_t)(u >> 16);
}

__device__ __forceinline__ float exp2_fast(float x) {
    float r; asm("v_exp_f32 %0, %1" : "=v"(r) : "v"(x)); return r;
}

// ---------------------------------------------------------------------------
// Fused f32->bf16 conversion of 7 tensors + int-mask -> float-bias plane.
// ---------------------------------------------------------------------------
struct CvtArgs {
    const float* src[7];
    ushort_t*    dst[7];
    int          n[7];
    const int*   msrc;   // int mask  [B*S]
    float*       mdst;   // float bias [B*S]: mask? 0 : -1e9
};

__global__ __launch_bounds__(256) void cvt_all(CvtArgs a)
{
    const int y = blockIdx.y;
    if (y == 7) {
        int i = (blockIdx.x * 256 + threadIdx.x) * 4;
        if (i >= BATCH * SEQ) return;
        int4 m = *(const int4*)(a.msrc + i);
        float4 o;
        o.x = m.x ? 0.f : -1e9f;
        o.y = m.y ? 0.f : -1e9f;
        o.z = m.z ? 0.f : -1e9f;
        o.w = m.w ? 0.f : -1e9f;
        *(float4*)(a.mdst + i) = o;
        return;
    }
    const int n = a.n[y];
    int i = (blockIdx.x * 256 + threadIdx.x) * 4;
    if (i >= n) return;
    const float* in = a.src[y];
    ushort_t* out = a.dst[y];
    float4 v = *(const float4*)(in + i);
    ushort4 o;
    o.x = f2bf(v.x); o.y = f2bf(v.y); o.z = f2bf(v.z); o.w = f2bf(v.w);
    *(ushort4*)(out + i) = o;
}

// ---------------------------------------------------------------------------
// Fused QKV projections, all-bf16 operands. 1-D grid 768, XCD-chunked:
//   xcd = f&7 owns by ∈ [4*xcd, 4*xcd+4) x all 24 n-blocks.
//   n0 <1024: Qf (A=Qb, bq, epilogue scale log2e/32)
//   <2048:    Kf (A=Kb, bk)
//   else:     Vt DIRECT (A=Vb, bv) — transposed write [(b*16+h)*64+dh][s].
// 128x128 tile, BK=64, global_load_lds staging, XOR-slot swizzle (verified).
// ---------------------------------------------------------------------------
__global__ __launch_bounds__(256) void gemm_qkv(
    const ushort_t* __restrict__ Qb, const ushort_t* __restrict__ Kb,
    const ushort_t* __restrict__ Vb, const ushort_t* __restrict__ Wcat,
    const float* __restrict__ bq, const float* __restrict__ bk,
    const float* __restrict__ bv,
    ushort_t* __restrict__ Qf, ushort_t* __restrict__ Kf,
    ushort_t* __restrict__ Vt)
{
    __shared__ ushort_t As[128 * 64];  // 16 KB, [row][slot], slot = k8 ^ (row&7)
    __shared__ ushort_t Bs[128 * 64];  // 16 KB

    const int t = threadIdx.x;
    const int lane = t & 63, w = t >> 6;
    const int x = lane & 15, y = lane >> 4;
    const int wm = (w >> 1) * 64, wn = (w & 1) * 64;

    const int f   = blockIdx.x;
    const int xcd = f & 7;
    const int idx = f >> 3;                     // 0..95
    const int m0  = (((xcd << 2) + (idx & 3)) << 7);
    const int n0  = (idx >> 2) << 7;            // 0..2944

    const ushort_t* Ab; const float* bp;
    if (n0 < 1024)      { Ab = Qb; bp = bq; }
    else if (n0 < 2048) { Ab = Kb; bp = bk; }
    else                { Ab = Vb; bp = bv; }
    const int ncol0 = n0 & 1023;

    floatx4 acc[4][4] = {};

    for (int kt = 0; kt < 16; ++kt) {
        const int k0 = kt * 64;

        #pragma unroll
        for (int j = 0; j < 4; ++j) {   // A stage
            int i   = (w << 2) + j;
            int c   = (i << 6) + lane;
            int row = c >> 3;
            int s   = c & 7;
            int k8  = s ^ (row & 7);
            const ushort_t* g = Ab + (size_t)(m0 + row) * DF + k0 + (k8 << 3);
            __builtin_amdgcn_global_load_lds(
                (const __attribute__((address_space(1))) unsigned int*)g,
                (__attribute__((address_space(3))) unsigned int*)(As + (i << 9)),
                16, 0, 0);
        }
        #pragma unroll
        for (int j = 0; j < 4; ++j) {   // B stage
            int i   = (w << 2) + j;
            int c   = (i << 6) + lane;
            int row = c >> 3;
            int s   = c & 7;
            int k8  = s ^ (row & 7);
            const ushort_t* g = Wcat + (size_t)(n0 + row) * DF + k0 + (k8 << 3);
            __builtin_amdgcn_global_load_lds(
                (const __attribute__((address_space(1))) unsigned int*)g,
                (__attribute__((address_space(3))) unsigned int*)(Bs + (i << 9)),
                16, 0, 0);
        }
        __syncthreads();

        #pragma unroll
        for (int kh = 0; kh < 2; ++kh) {
            const int slot = ((kh << 2) + y) ^ (x & 7);
            short8 af[4], bfr[4];
            #pragma unroll
            for (int mt = 0; mt < 4; ++mt)
                af[mt] = *(const short8*)(As + (wm + (mt << 4) + x) * 64 + slot * 8);
            #pragma unroll
            for (int nt = 0; nt < 4; ++nt)
                bfr[nt] = *(const short8*)(Bs + (wn + (nt << 4) + x) * 64 + slot * 8);
            __builtin_amdgcn_s_setprio(1);
            #pragma unroll
            for (int mt = 0; mt < 4; ++mt)
                #pragma unroll
                for (int nt = 0; nt < 4; ++nt)
                    acc[mt][nt] = __builtin_amdgcn_mfma_f32_16x16x32_bf16(
                        af[mt], bfr[nt], acc[mt][nt], 0, 0, 0);
            __builtin_amdgcn_s_setprio(0);
        }
        __syncthreads();
    }

    float bvv[4];
    #pragma unroll
    for (int nt = 0; nt < 4; ++nt) bvv[nt] = bp[ncol0 + wn + (nt << 4) + x];

    if (n0 < 2048) {
        ushort_t* outp = (n0 < 1024) ? Qf : Kf;
        const float osc = (n0 < 1024) ? 0.0450842200f : 1.0f;  // log2(e)/32
        #pragma unroll
        for (int mt = 0; mt < 4; ++mt) {
            #pragma unroll
            for (int r = 0; r < 4; ++r) {
                const size_t grow = (size_t)(m0 + wm + (mt << 4) + (y << 2) + r) * DF;
                #pragma unroll
                for (int nt = 0; nt < 4; ++nt)
                    outp[grow + ncol0 + wn + (nt << 4) + x] =
                        f2bf((acc[mt][nt][r] + bvv[nt]) * osc);
            }
        }
    } else {
        // V: direct transposed write to Vt[(b*16+h)*64+dh][s]
        #pragma unroll
        for (int mt = 0; mt < 4; ++mt) {
            int m   = m0 + wm + (mt << 4) + (y << 2);  // +r are consecutive s
            int bb2 = m >> 11;
            int s0  = m & 2047;
            #pragma unroll
            for (int nt = 0; nt < 4; ++nt) {
                int col = ncol0 + wn + (nt << 4) + x;  // h*64+dh
                ushort4 pk;
                pk.x = f2bf(acc[mt][nt][0] + bvv[nt]);
                pk.y = f2bf(acc[mt][nt][1] + bvv[nt]);
                pk.z = f2bf(acc[mt][nt][2] + bvv[nt]);
                pk.w = f2bf(acc[mt][nt][3] + bvv[nt]);
                *(ushort4*)(Vt + ((size_t)(bb2 << 10) + col) * 2048 + s0) = pk;
            }
        }
    }
}

// ---------------------------------------------------------------------------
// Out-projection: C[4096,1024] = Xr @ Wo^T + bo, f32 out.
// 1-D grid 512, XCD-chunked. Tile 128(M) x 64(N). Wave-tile 64x32.
// ---------------------------------------------------------------------------
__global__ __launch_bounds__(256) void gemm_out(
    const ushort_t* __restrict__ Xr, const ushort_t* __restrict__ Wb,
    const float* __restrict__ bias, float* __restrict__ C)
{
    __shared__ ushort_t As[128 * 64];  // 16 KB
    __shared__ ushort_t Bs[64 * 64];   // 8 KB

    const int t = threadIdx.x;
    const int lane = t & 63, w = t >> 6;
    const int x = lane & 15, y = lane >> 4;
    const int wm = (w >> 1) * 64, wn = (w & 1) * 32;

    const int f   = blockIdx.x;
    const int xcd = f & 7;
    const int idx = f >> 3;                    // 0..63
    const int m0  = (((xcd << 2) + (idx & 3)) << 7);
    const int n0  = (idx >> 2) << 6;           // 0..960

    floatx4 acc[4][2] = {};

    for (int kt = 0; kt < 16; ++kt) {
        const int k0 = kt * 64;

        #pragma unroll
        for (int j = 0; j < 4; ++j) {   // A stage: 16 KB
            int i   = (w << 2) + j;
            int c   = (i << 6) + lane;
            int row = c >> 3;
            int s   = c & 7;
            int k8  = s ^ (row & 7);
            const ushort_t* g = Xr + (size_t)(m0 + row) * DF + k0 + (k8 << 3);
            __builtin_amdgcn_global_load_lds(
                (const __attribute__((address_space(1))) unsigned int*)g,
                (__attribute__((address_space(3))) unsigned int*)(As + (i << 9)),
                16, 0, 0);
        }
        #pragma unroll
        for (int j = 0; j < 2; ++j) {   // B stage: 8 KB
            int i   = (w << 1) + j;
            int c   = (i << 6) + lane;
            int row = c >> 3;
            int s   = c & 7;
            int k8  = s ^ (row & 7);
            const ushort_t* g = Wb + (size_t)(n0 + row) * DF + k0 + (k8 << 3);
            __builtin_amdgcn_global_load_lds(
                (const __attribute__((address_space(1))) unsigned int*)g,
                (__attribute__((address_space(3))) unsigned int*)(Bs + (i << 9)),
                16, 0, 0);
        }
        __syncthreads();

        #pragma unroll
        for (int kh = 0; kh < 2; ++kh) {
            const int slot = ((kh << 2) + y) ^ (x & 7);
            short8 af[4], bfr[2];
            #pragma unroll
            for (int mt = 0; mt < 4; ++mt)
                af[mt] = *(const short8*)(As + (wm + (mt << 4) + x) * 64 + slot * 8);
            #pragma unroll
            for (int nt = 0; nt < 2; ++nt)
                bfr[nt] = *(const short8*)(Bs + (wn + (nt << 4) + x) * 64 + slot * 8);
            __builtin_amdgcn_s_setprio(1);
            #pragma unroll
            for (int mt = 0; mt < 4; ++mt)
                #pragma unroll
                for (int nt = 0; nt < 2; ++nt)
                    acc[mt][nt] = __builtin_amdgcn_mfma_f32_16x16x32_bf16(
                        af[mt], bfr[nt], acc[mt][nt], 0, 0, 0);
            __builtin_amdgcn_s_setprio(0);
        }
        __syncthreads();
    }

    float bvv[2];
    #pragma unroll
    for (int nt = 0; nt < 2; ++nt) bvv[nt] = bias[n0 + wn + (nt << 4) + x];

    #pragma unroll
    for (int mt = 0; mt < 4; ++mt) {
        #pragma unroll
        for (int r = 0; r < 4; ++r) {
            const size_t grow = (size_t)(m0 + wm + (mt << 4) + (y << 2) + r) * DF;
            #pragma unroll
            for (int nt = 0; nt < 2; ++nt)
                C[grow + n0 + wn + (nt << 4) + x] = acc[mt][nt][r] + bvv[nt];
        }
    }
}

// ---------------------------------------------------------------------------
// Attention v2: 32x32x16 MFMA, in-register P.
// Block = 4 waves x 32 q = 128 q; 64-key tiles; K/V double-buffered in LDS,
// one __syncthreads per iter. Grid 512 = 16 qb x 32 hb; hb = f&31 keeps
// XCD co-location (f%8 = hb%8).
//
// Layouts (32x32x16): A/B frag lane l: row/col = l&31, k = (l>>5)*8 + j.
// C/D: col = l&31, row = (reg&3) + 8*(reg>>2) + 4*(l>>5).
// QK^T: mfma(kf, qfrag) -> S^T[key][q]: every lane's 32 values share q =
// w*32 + (l&31). Softmax in-register; P pairs via v_cvt_pk_bf16_f32; the
// PV A-frag (P[q][key]: row = l&31 = q matches!) is assembled with two
// v_permlane32_swap_b32 per 16-key chunk:
//   swap(pk[b], pk[b+2]) -> (u0, u2); swap(pk[b+1], pk[b+3]) -> (u1, u3).
// PV: mfma(pa, vf) -> O[q][dh], col = l&31 = dh.
// dsum: one shfl_xor(32); rdv broadcast via dead Qs region (wave-local).
// LDS 48 KB: Qs 16 + Ks dbuf 16 + Vs dbuf 16.
// ---------------------------------------------------------------------------
__global__ __launch_bounds__(256) void attn_mfma(
    const ushort_t* __restrict__ Qf, const ushort_t* __restrict__ Kf,
    const ushort_t* __restrict__ Vt, const float* __restrict__ maskb,
    ushort_t* __restrict__ Xr)
{
    __shared__ ushort_t Qs[128 * 64];     // 16 KB; rdv scratch after prologue
    __shared__ ushort_t Ks[2][64 * 64];   // 16 KB double-buffered
    __shared__ ushort_t Vs[2][64 * 64];   // 16 KB double-buffered

    const int t = threadIdx.x;
    const int lane = t & 63, w = t >> 6;
    const int l31 = lane & 31, hi = lane >> 5;

    const int f  = blockIdx.x;
    const int hb = f & 31;          // b*16 + h
    const int b  = hb >> 4;
    const int h  = hb & 15;
    const int q0 = (f >> 5) << 7;   // 128-q block base

    const size_t qkbase = ((size_t)b * SEQ) * DF + (size_t)h * DH;
    const size_t vbase  = ((size_t)(b * NH + h) * DH) * SEQ;
    const int mbase = b * SEQ;

    // ---- prologue: Q stage (16 KB, 4 calls/wave) + K/V tile 0 ----
    #pragma unroll
    for (int j = 0; j < 4; ++j) {
        int i   = (w << 2) + j;          // 0..15
        int c   = (i << 6) + lane;
        int row = c >> 3;                // 0..127
        int k8  = (c & 7) ^ (row & 7);
        const ushort_t* g = Qf + qkbase + (size_t)(q0 + row) * DF + (k8 << 3);
        __builtin_amdgcn_global_load_lds(
            (const __attribute__((address_space(1))) unsigned int*)g,
            (__attribute__((address_space(3))) unsigned int*)(Qs + (i << 9)),
            16, 0, 0);
    }
    #pragma unroll
    for (int j = 0; j < 4; ++j) {
        int i   = (w << 2) + j;          // i<8: K rows, else V rows
        int c   = (i << 6) + lane;
        int row = (c >> 3) & 63;
        int k8  = (c & 7) ^ (row & 7);
        if (i < 8) {
            const ushort_t* g = Kf + qkbase + (size_t)row * DF + (k8 << 3);
            __builtin_amdgcn_global_load_lds(
                (const __attribute__((address_space(1))) unsigned int*)g,
                (__attribute__((address_space(3))) unsigned int*)(Ks[0] + (i << 9)),
                16, 0, 0);
        } else {
            const ushort_t* g = Vt + vbase + (size_t)row * SEQ + (k8 << 3);
            __builtin_amdgcn_global_load_lds(
                (const __attribute__((address_space(1))) unsigned int*)g,
                (__attribute__((address_space(3))) unsigned int*)(Vs[0] + ((i - 8) << 9)),
                16, 0, 0);
        }
    }
    __syncthreads();

    // qfrag[kc]: B-frag of Q^T — row = wave q-strip + l31, dh chunk kc*16+hi*8
    short8 qfrag[4];
    const int qrow = (w << 5) + l31;
    #pragma unroll
    for (int kc = 0; kc < 4; ++kc) {
        int slot = ((kc << 1) + hi) ^ (qrow & 7);
        qfrag[kc] = *(const short8*)(Qs + qrow * 64 + slot * 8);
    }

    floatx16 oacc[2] = {};              // [dhb]: O[q][dhb*32 + l31]
    float ds0 = 0.f, ds1 = 0.f, ds2 = 0.f, ds3 = 0.f;

    for (int kt = 0; kt < 32; ++kt) {
        const int cur = kt & 1;
        const int k0 = kt << 6;

        // ---- mask-bias loads (issued first: vmcnt retires in order) ----
        // thread's key r (reg) in block kb: kb*32 + (r&3) + 8*(r>>2) + 4*hi
        float mbf[2][16];
        #pragma unroll
        for (int kb = 0; kb < 2; ++kb)
            #pragma unroll
            for (int u = 0; u < 4; ++u) {
                float4 v = *(const float4*)(
                    maskb + mbase + k0 + (kb << 5) + (u << 3) + (hi << 2));
                mbf[kb][(u << 2) + 0] = v.x;
                mbf[kb][(u << 2) + 1] = v.y;
                mbf[kb][(u << 2) + 2] = v.z;
                mbf[kb][(u << 2) + 3] = v.w;
            }

        // ---- stage NEXT K/V tile into the other buffer ----
        if (kt < 31) {
            const int k0n = (kt + 1) << 6;
            ushort_t* Kd = Ks[cur ^ 1];
            ushort_t* Vd = Vs[cur ^ 1];
            #pragma unroll
            for (int j = 0; j < 4; ++j) {
                int i   = (w << 2) + j;
                int c   = (i << 6) + lane;
                int row = (c >> 3) & 63;
                int k8  = (c & 7) ^ (row & 7);
                if (i < 8) {
                    const ushort_t* g = Kf + qkbase + (size_t)(k0n + row) * DF + (k8 << 3);
                    __builtin_amdgcn_global_load_lds(
                        (const __attribute__((address_space(1))) unsigned int*)g,
                        (__attribute__((address_space(3))) unsigned int*)(Kd + (i << 9)),
                        16, 0, 0);
                } else {
                    const ushort_t* g = Vt + vbase + (size_t)row * SEQ + k0n + (k8 << 3);
                    __builtin_amdgcn_global_load_lds(
                        (const __attribute__((address_space(1))) unsigned int*)g,
                        (__attribute__((address_space(3))) unsigned int*)(Vd + ((i - 8) << 9)),
                        16, 0, 0);
                }
            }
        }

        const ushort_t* Kc = Ks[cur];
        const ushort_t* Vc = Vs[cur];

        // ---- S^T = K·Q^T: sacc[kb] = S^T[kb*32 + rows][q] ----
        floatx16 sacc[2] = {};
        #pragma unroll
        for (int kc = 0; kc < 4; ++kc) {
            #pragma unroll
            for (int kb = 0; kb < 2; ++kb) {
                int row  = (kb << 5) + l31;
                int slot = ((kc << 1) + hi) ^ (row & 7);
                short8 kf = *(const short8*)(Kc + row * 64 + slot * 8);
                sacc[kb] = __builtin_amdgcn_mfma_f32_32x32x16_bf16(
                    kf, qfrag[kc], sacc[kb], 0, 0, 0);
            }
        }

        // ---- softmax + cvt_pk + permlane32_swap -> PV A-frags ----
        short8 pa[4];
        #pragma unroll
        for (int kb = 0; kb < 2; ++kb) {
            float p[16];
            #pragma unroll
            for (int r = 0; r < 16; ++r)
                p[r] = exp2_fast(sacc[kb][r] + mbf[kb][r]);
            ds0 += (p[0] + p[1])  + (p[2] + p[3]);
            ds1 += (p[4] + p[5])  + (p[6] + p[7]);
            ds2 += (p[8] + p[9])  + (p[10] + p[11]);
            ds3 += (p[12] + p[13]) + (p[14] + p[15]);
            unsigned int pk[8];
            #pragma unroll
            for (int i = 0; i < 8; ++i)
                asm("v_cvt_pk_bf16_f32 %0, %1, %2"
                    : "=v"(pk[i]) : "v"(p[2 * i]), "v"(p[2 * i + 1]));
            #pragma unroll
            for (int cc = 0; cc < 2; ++cc) {
                unsigned int a0 = pk[(cc << 2) + 0], b0 = pk[(cc << 2) + 2];
                unsigned int a1 = pk[(cc << 2) + 1], b1 = pk[(cc << 2) + 3];
                asm("v_permlane32_swap_b32 %0, %1" : "+v"(a0), "+v"(b0));
                asm("v_permlane32_swap_b32 %0, %1" : "+v"(a1), "+v"(b1));
                union { unsigned int u[4]; short8 s; } pu;
                pu.u[0] = a0; pu.u[1] = a1; pu.u[2] = b0; pu.u[3] = b1;
                pa[(kb << 1) + cc] = pu.s;
            }
        }

        // ---- PV: O[q][dh] += P · V ----
        #pragma unroll
        for (int kc2 = 0; kc2 < 4; ++kc2) {
            #pragma unroll
            for (int dhb = 0; dhb < 2; ++dhb) {
                int row  = (dhb << 5) + l31;
                int slot = ((kc2 << 1) + hi) ^ (row & 7);
                short8 vf = *(const short8*)(Vc + row * 64 + slot * 8);
                oacc[dhb] = __builtin_amdgcn_mfma_f32_32x32x16_bf16(
                    pa[kc2], vf, oacc[dhb], 0, 0, 0);
            }
        }

        __syncthreads();   // next tile staged & visible; cur-buf reads drained
    }

    // ---- epilogue ----
    float dsum = (ds0 + ds1) + (ds2 + ds3);   // partial for q = w*32 + l31
    dsum += __shfl_xor(dsum, 32, 64);         // hi halves hold complementary keys
    float rdv = 1.0f / dsum;

    // share rdv across the 4*hi+reg q-pattern via dead Qs (wave-local region)
    float* dls = (float*)Qs + (w << 5);       // 32 floats per wave
    dls[l31] = rdv;                           // both hi halves write same value
    float4 rv[4];
    #pragma unroll
    for (int u = 0; u < 4; ++u)
        rv[u] = *(const float4*)(dls + (u << 3) + (hi << 2));

    #pragma unroll
    for (int u = 0; u < 4; ++u) {
        #pragma unroll
        for (int r2 = 0; r2 < 4; ++r2) {
            const int q = q0 + (w << 5) + (u << 3) + (hi << 2) + r2;
            const float rr = (r2 == 0) ? rv[u].x : (r2 == 1) ? rv[u].y
                           : (r2 == 2) ? rv[u].z : rv[u].w;
            #pragma unroll
            for (int dhb = 0; dhb < 2; ++dhb)
                Xr[qkbase + (size_t)q * DF + (dhb << 5) + l31] =
                    f2bf(oacc[dhb][(u << 2) + r2] * rr);
        }
    }
}

// ---------------------------------------------------------------------------
extern "C" void kernel_launch(void* const* d_in, const int* in_sizes, int n_in,
                              void* d_out, int out_size, void* d_ws, size_t ws_size,
                              hipStream_t stream)
{
    const float* Q    = (const float*)d_in[0];
    const float* K    = (const float*)d_in[1];
    const float* V    = (const float*)d_in[2];
    const int*   mask = (const int*)d_in[3];
    const float* Wq   = (const float*)d_in[4];
    const float* bq   = (const float*)d_in[5];
    const float* Wk   = (const float*)d_in[6];
    const float* bk   = (const float*)d_in[7];
    const float* Wv   = (const float*)d_in[8];
    const float* bv   = (const float*)d_in[9];
    const float* Wo   = (const float*)d_in[10];
    const float* bo   = (const float*)d_in[11];
    float* out = (float*)d_out;

    // ws (48 MB): Wcat 8 + Qf 8 + Kf 8 + Vt 8 + Xr 8 + Qb 8.
    // Aliases: Kb = Xr (dead before attn writes), Vb = d_out (first 8 MB,
    // dead before gemm_out writes), maskb = d_out second half (16 KB; attn
    // reads it before gemm_out overwrites d_out — stream-ordered).
    ushort_t* Wqb = (ushort_t*)d_ws;
    ushort_t* Wkb = Wqb + (1 << 20);
    ushort_t* Wvb = Wkb + (1 << 20);
    ushort_t* Wob = Wvb + (1 << 20);
    ushort_t* Qf  = Wob + (1 << 20);
    ushort_t* Kf  = Qf + (size_t)MROWS * DF;
    ushort_t* Vt  = Kf + (size_t)MROWS * DF;
    ushort_t* Xr  = Vt + (size_t)MROWS * DF;
    ushort_t* Qb  = Xr + (size_t)MROWS * DF;
    ushort_t* Kb  = Xr;
    ushort_t* Vb  = (ushort_t*)d_out;
    float*    maskb = (float*)((ushort_t*)d_out + (size_t)(1 << 22));  // +8 MB

    const int nin = MROWS * DF;  // 4M
    const int nw  = DF * DF;     // 1M

    CvtArgs ca;
    ca.src[0] = Q;  ca.dst[0] = Qb;  ca.n[0] = nin;
    ca.src[1] = K;  ca.dst[1] = Kb;  ca.n[1] = nin;
    ca.src[2] = V;  ca.dst[2] = Vb;  ca.n[2] = nin;
    ca.src[3] = Wq; ca.dst[3] = Wqb; ca.n[3] = nw;
    ca.src[4] = Wk; ca.dst[4] = Wkb; ca.n[4] = nw;
    ca.src[5] = Wv; ca.dst[5] = Wvb; ca.n[5] = nw;
    ca.src[6] = Wo; ca.dst[6] = Wob; ca.n[6] = nw;
    ca.msrc = mask;
    ca.mdst = maskb;

    dim3 blk(256);
    cvt_all<<<dim3(nin / 1024, 8), blk, 0, stream>>>(ca);

    gemm_qkv<<<dim3(768), blk, 0, stream>>>(Qb, Kb, Vb, Wqb, bq, bk, bv,
                                            Qf, Kf, Vt);

    attn_mfma<<<dim3(512), blk, 0, stream>>>(Qf, Kf, Vt, maskb, Xr);

    gemm_out<<<dim3(512), blk, 0, stream>>>(Xr, Wob, bo, out);
}

// Round 7
// 229.314 us; speedup vs baseline: 1.4885x; 1.0112x over previous
//
#include <hip/hip_runtime.h>

// MultiHeadedAttention B=2,S=2048,D=1024,H=16,Dh=64 — f32 in/out.
// Round 14 (attn: 128-key staging, 2 sub-tiles per barrier):
//   - K/V staged 128 keys/iter (16 iters, 16 barriers — was 32). Each iter
//     computes two 64-key sub-tiles inside ONE barrier window so the
//     compiler can overlap sub0 softmax (VALU/TRANS) with sub1 QK^T (MFMA).
//     At 2 blocks/CU (grid-capped) the extra LDS (48->80 KB) is free.
//   - mask-bias loads moved inside each sub-body (shorter live ranges).
// R13: 32x32x16 MFMA, in-register P via cvt_pk + permlane32_swap. R12: GEMMs
// XCD-chunked 1-D grids + setprio. R11: attn XCD co-location (FETCH 69.7->
// 12.4 MB verified). R8: exp2 softmax (log2e/32 folded into Q), mask-bias
// plane. Frag layouts + XOR-slot swizzle HW-verified (rounds 3-6, m74/m101).

typedef unsigned short ushort_t;
typedef __attribute__((ext_vector_type(8)))  short short8;
typedef __attribute__((ext_vector_type(4)))  float floatx4;
typedef __attribute__((ext_vector_type(16))) float floatx16;

#define BATCH 2
#define SEQ   2048
#define DF    1024
#define NH    16
#define DH    64
#define MROWS 4096

__device__ __forceinline__ ushort_t f2bf(float f) {
    unsigned int u = __float_as_uint(f);
    u += 0x7FFFu + ((u >> 16) & 1u);   // RNE
    return (ushort_t)(u >> 16);
}

__device__ __forceinline__ float exp2_fast(float x) {
    float r; asm("v_exp_f32 %0, %1" : "=v"(r) : "v"(x)); return r;
}

// ---------------------------------------------------------------------------
// Fused f32->bf16 conversion of 7 tensors + int-mask -> float-bias plane.
// ---------------------------------------------------------------------------
struct CvtArgs {
    const float* src[7];
    ushort_t*    dst[7];
    int          n[7];
    const int*   msrc;   // int mask  [B*S]
    float*       mdst;   // float bias [B*S]: mask? 0 : -1e9
};

__global__ __launch_bounds__(256) void cvt_all(CvtArgs a)
{
    const int y = blockIdx.y;
    if (y == 7) {
        int i = (blockIdx.x * 256 + threadIdx.x) * 4;
        if (i >= BATCH * SEQ) return;
        int4 m = *(const int4*)(a.msrc + i);
        float4 o;
        o.x = m.x ? 0.f : -1e9f;
        o.y = m.y ? 0.f : -1e9f;
        o.z = m.z ? 0.f : -1e9f;
        o.w = m.w ? 0.f : -1e9f;
        *(float4*)(a.mdst + i) = o;
        return;
    }
    const int n = a.n[y];
    int i = (blockIdx.x * 256 + threadIdx.x) * 4;
    if (i >= n) return;
    const float* in = a.src[y];
    ushort_t* out = a.dst[y];
    float4 v = *(const float4*)(in + i);
    ushort4 o;
    o.x = f2bf(v.x); o.y = f2bf(v.y); o.z = f2bf(v.z); o.w = f2bf(v.w);
    *(ushort4*)(out + i) = o;
}

// ---------------------------------------------------------------------------
// Fused QKV projections, all-bf16 operands. 1-D grid 768, XCD-chunked:
//   xcd = f&7 owns by ∈ [4*xcd, 4*xcd+4) x all 24 n-blocks.
//   n0 <1024: Qf (A=Qb, bq, epilogue scale log2e/32)
//   <2048:    Kf (A=Kb, bk)
//   else:     Vt DIRECT (A=Vb, bv) — transposed write [(b*16+h)*64+dh][s].
// 128x128 tile, BK=64, global_load_lds staging, XOR-slot swizzle (verified).
// ---------------------------------------------------------------------------
__global__ __launch_bounds__(256) void gemm_qkv(
    const ushort_t* __restrict__ Qb, const ushort_t* __restrict__ Kb,
    const ushort_t* __restrict__ Vb, const ushort_t* __restrict__ Wcat,
    const float* __restrict__ bq, const float* __restrict__ bk,
    const float* __restrict__ bv,
    ushort_t* __restrict__ Qf, ushort_t* __restrict__ Kf,
    ushort_t* __restrict__ Vt)
{
    __shared__ ushort_t As[128 * 64];  // 16 KB, [row][slot], slot = k8 ^ (row&7)
    __shared__ ushort_t Bs[128 * 64];  // 16 KB

    const int t = threadIdx.x;
    const int lane = t & 63, w = t >> 6;
    const int x = lane & 15, y = lane >> 4;
    const int wm = (w >> 1) * 64, wn = (w & 1) * 64;

    const int f   = blockIdx.x;
    const int xcd = f & 7;
    const int idx = f >> 3;                     // 0..95
    const int m0  = (((xcd << 2) + (idx & 3)) << 7);
    const int n0  = (idx >> 2) << 7;            // 0..2944

    const ushort_t* Ab; const float* bp;
    if (n0 < 1024)      { Ab = Qb; bp = bq; }
    else if (n0 < 2048) { Ab = Kb; bp = bk; }
    else                { Ab = Vb; bp = bv; }
    const int ncol0 = n0 & 1023;

    floatx4 acc[4][4] = {};

    for (int kt = 0; kt < 16; ++kt) {
        const int k0 = kt * 64;

        #pragma unroll
        for (int j = 0; j < 4; ++j) {   // A stage
            int i   = (w << 2) + j;
            int c   = (i << 6) + lane;
            int row = c >> 3;
            int s   = c & 7;
            int k8  = s ^ (row & 7);
            const ushort_t* g = Ab + (size_t)(m0 + row) * DF + k0 + (k8 << 3);
            __builtin_amdgcn_global_load_lds(
                (const __attribute__((address_space(1))) unsigned int*)g,
                (__attribute__((address_space(3))) unsigned int*)(As + (i << 9)),
                16, 0, 0);
        }
        #pragma unroll
        for (int j = 0; j < 4; ++j) {   // B stage
            int i   = (w << 2) + j;
            int c   = (i << 6) + lane;
            int row = c >> 3;
            int s   = c & 7;
            int k8  = s ^ (row & 7);
            const ushort_t* g = Wcat + (size_t)(n0 + row) * DF + k0 + (k8 << 3);
            __builtin_amdgcn_global_load_lds(
                (const __attribute__((address_space(1))) unsigned int*)g,
                (__attribute__((address_space(3))) unsigned int*)(Bs + (i << 9)),
                16, 0, 0);
        }
        __syncthreads();

        #pragma unroll
        for (int kh = 0; kh < 2; ++kh) {
            const int slot = ((kh << 2) + y) ^ (x & 7);
            short8 af[4], bfr[4];
            #pragma unroll
            for (int mt = 0; mt < 4; ++mt)
                af[mt] = *(const short8*)(As + (wm + (mt << 4) + x) * 64 + slot * 8);
            #pragma unroll
            for (int nt = 0; nt < 4; ++nt)
                bfr[nt] = *(const short8*)(Bs + (wn + (nt << 4) + x) * 64 + slot * 8);
            __builtin_amdgcn_s_setprio(1);
            #pragma unroll
            for (int mt = 0; mt < 4; ++mt)
                #pragma unroll
                for (int nt = 0; nt < 4; ++nt)
                    acc[mt][nt] = __builtin_amdgcn_mfma_f32_16x16x32_bf16(
                        af[mt], bfr[nt], acc[mt][nt], 0, 0, 0);
            __builtin_amdgcn_s_setprio(0);
        }
        __syncthreads();
    }

    float bvv[4];
    #pragma unroll
    for (int nt = 0; nt < 4; ++nt) bvv[nt] = bp[ncol0 + wn + (nt << 4) + x];

    if (n0 < 2048) {
        ushort_t* outp = (n0 < 1024) ? Qf : Kf;
        const float osc = (n0 < 1024) ? 0.0450842200f : 1.0f;  // log2(e)/32
        #pragma unroll
        for (int mt = 0; mt < 4; ++mt) {
            #pragma unroll
            for (int r = 0; r < 4; ++r) {
                const size_t grow = (size_t)(m0 + wm + (mt << 4) + (y << 2) + r) * DF;
                #pragma unroll
                for (int nt = 0; nt < 4; ++nt)
                    outp[grow + ncol0 + wn + (nt << 4) + x] =
                        f2bf((acc[mt][nt][r] + bvv[nt]) * osc);
            }
        }
    } else {
        // V: direct transposed write to Vt[(b*16+h)*64+dh][s]
        #pragma unroll
        for (int mt = 0; mt < 4; ++mt) {
            int m   = m0 + wm + (mt << 4) + (y << 2);  // +r are consecutive s
            int bb2 = m >> 11;
            int s0  = m & 2047;
            #pragma unroll
            for (int nt = 0; nt < 4; ++nt) {
                int col = ncol0 + wn + (nt << 4) + x;  // h*64+dh
                ushort4 pk;
                pk.x = f2bf(acc[mt][nt][0] + bvv[nt]);
                pk.y = f2bf(acc[mt][nt][1] + bvv[nt]);
                pk.z = f2bf(acc[mt][nt][2] + bvv[nt]);
                pk.w = f2bf(acc[mt][nt][3] + bvv[nt]);
                *(ushort4*)(Vt + ((size_t)(bb2 << 10) + col) * 2048 + s0) = pk;
            }
        }
    }
}

// ---------------------------------------------------------------------------
// Out-projection: C[4096,1024] = Xr @ Wo^T + bo, f32 out.
// 1-D grid 512, XCD-chunked. Tile 128(M) x 64(N). Wave-tile 64x32.
// ---------------------------------------------------------------------------
__global__ __launch_bounds__(256) void gemm_out(
    const ushort_t* __restrict__ Xr, const ushort_t* __restrict__ Wb,
    const float* __restrict__ bias, float* __restrict__ C)
{
    __shared__ ushort_t As[128 * 64];  // 16 KB
    __shared__ ushort_t Bs[64 * 64];   // 8 KB

    const int t = threadIdx.x;
    const int lane = t & 63, w = t >> 6;
    const int x = lane & 15, y = lane >> 4;
    const int wm = (w >> 1) * 64, wn = (w & 1) * 32;

    const int f   = blockIdx.x;
    const int xcd = f & 7;
    const int idx = f >> 3;                    // 0..63
    const int m0  = (((xcd << 2) + (idx & 3)) << 7);
    const int n0  = (idx >> 2) << 6;           // 0..960

    floatx4 acc[4][2] = {};

    for (int kt = 0; kt < 16; ++kt) {
        const int k0 = kt * 64;

        #pragma unroll
        for (int j = 0; j < 4; ++j) {   // A stage: 16 KB
            int i   = (w << 2) + j;
            int c   = (i << 6) + lane;
            int row = c >> 3;
            int s   = c & 7;
            int k8  = s ^ (row & 7);
            const ushort_t* g = Xr + (size_t)(m0 + row) * DF + k0 + (k8 << 3);
            __builtin_amdgcn_global_load_lds(
                (const __attribute__((address_space(1))) unsigned int*)g,
                (__attribute__((address_space(3))) unsigned int*)(As + (i << 9)),
                16, 0, 0);
        }
        #pragma unroll
        for (int j = 0; j < 2; ++j) {   // B stage: 8 KB
            int i   = (w << 1) + j;
            int c   = (i << 6) + lane;
            int row = c >> 3;
            int s   = c & 7;
            int k8  = s ^ (row & 7);
            const ushort_t* g = Wb + (size_t)(n0 + row) * DF + k0 + (k8 << 3);
            __builtin_amdgcn_global_load_lds(
                (const __attribute__((address_space(1))) unsigned int*)g,
                (__attribute__((address_space(3))) unsigned int*)(Bs + (i << 9)),
                16, 0, 0);
        }
        __syncthreads();

        #pragma unroll
        for (int kh = 0; kh < 2; ++kh) {
            const int slot = ((kh << 2) + y) ^ (x & 7);
            short8 af[4], bfr[2];
            #pragma unroll
            for (int mt = 0; mt < 4; ++mt)
                af[mt] = *(const short8*)(As + (wm + (mt << 4) + x) * 64 + slot * 8);
            #pragma unroll
            for (int nt = 0; nt < 2; ++nt)
                bfr[nt] = *(const short8*)(Bs + (wn + (nt << 4) + x) * 64 + slot * 8);
            __builtin_amdgcn_s_setprio(1);
            #pragma unroll
            for (int mt = 0; mt < 4; ++mt)
                #pragma unroll
                for (int nt = 0; nt < 2; ++nt)
                    acc[mt][nt] = __builtin_amdgcn_mfma_f32_16x16x32_bf16(
                        af[mt], bfr[nt], acc[mt][nt], 0, 0, 0);
            __builtin_amdgcn_s_setprio(0);
        }
        __syncthreads();
    }

    float bvv[2];
    #pragma unroll
    for (int nt = 0; nt < 2; ++nt) bvv[nt] = bias[n0 + wn + (nt << 4) + x];

    #pragma unroll
    for (int mt = 0; mt < 4; ++mt) {
        #pragma unroll
        for (int r = 0; r < 4; ++r) {
            const size_t grow = (size_t)(m0 + wm + (mt << 4) + (y << 2) + r) * DF;
            #pragma unroll
            for (int nt = 0; nt < 2; ++nt)
                C[grow + n0 + wn + (nt << 4) + x] = acc[mt][nt][r] + bvv[nt];
        }
    }
}

// ---------------------------------------------------------------------------
// Attention v3: 32x32x16 MFMA, in-register P, 128-key staging.
// Block = 4 waves x 32 q = 128 q; grid 512 = 16 qb x 32 hb (XCD co-located).
// Per iteration (16 total): stage NEXT 128 keys (2 sub-tiles of 64) into
// buf^1, then compute BOTH sub-tiles of buf[cur] inside one barrier window
// (sub0 softmax VALU overlaps sub1 QK^T MFMA), then ONE __syncthreads.
// Sub-tile layout identical to R13: K sub [key&63][slot], V sub [dh][slot],
// slot XOR (row&7); sub s at byte offset s*8KB.
// LDS 80 KB: Qs 16 + Ks dbuf 32 + Vs dbuf 32 (2 blocks/CU — grid-capped
// anyway). P in registers via cvt_pk + permlane32_swap (T12).
// ---------------------------------------------------------------------------
__global__ __launch_bounds__(256) void attn_mfma(
    const ushort_t* __restrict__ Qf, const ushort_t* __restrict__ Kf,
    const ushort_t* __restrict__ Vt, const float* __restrict__ maskb,
    ushort_t* __restrict__ Xr)
{
    __shared__ ushort_t Qs[128 * 64];      // 16 KB; rdv scratch in epilogue
    __shared__ ushort_t Ks[2][2 * 64 * 64]; // 32 KB double-buffered, 2 subs
    __shared__ ushort_t Vs[2][2 * 64 * 64]; // 32 KB double-buffered, 2 subs

    const int t = threadIdx.x;
    const int lane = t & 63, w = t >> 6;
    const int l31 = lane & 31, hi = lane >> 5;

    const int f  = blockIdx.x;
    const int hb = f & 31;          // b*16 + h
    const int b  = hb >> 4;
    const int h  = hb & 15;
    const int q0 = (f >> 5) << 7;   // 128-q block base

    const size_t qkbase = ((size_t)b * SEQ) * DF + (size_t)h * DH;
    const size_t vbase  = ((size_t)(b * NH + h) * DH) * SEQ;
    const int mbase = b * SEQ;

    // ---- prologue: Q stage (16 KB) + K/V tile 0 (both subs) ----
    #pragma unroll
    for (int j = 0; j < 4; ++j) {
        int i   = (w << 2) + j;          // 0..15
        int c   = (i << 6) + lane;
        int row = c >> 3;                // 0..127
        int k8  = (c & 7) ^ (row & 7);
        const ushort_t* g = Qf + qkbase + (size_t)(q0 + row) * DF + (k8 << 3);
        __builtin_amdgcn_global_load_lds(
            (const __attribute__((address_space(1))) unsigned int*)g,
            (__attribute__((address_space(3))) unsigned int*)(Qs + (i << 9)),
            16, 0, 0);
    }
    #pragma unroll
    for (int j = 0; j < 4; ++j) {        // K: 16 chunks over 128 keys
        int i   = (w << 2) + j;          // 0..15; sub = i>>3
        int c   = (i << 6) + lane;
        int row = c >> 3;                // key 0..127
        int k8  = (c & 7) ^ (row & 7);
        const ushort_t* g = Kf + qkbase + (size_t)row * DF + (k8 << 3);
        __builtin_amdgcn_global_load_lds(
            (const __attribute__((address_space(1))) unsigned int*)g,
            (__attribute__((address_space(3))) unsigned int*)(
                Ks[0] + ((i >> 3) << 12) + ((i & 7) << 9)),
            16, 0, 0);
    }
    #pragma unroll
    for (int j = 0; j < 4; ++j) {        // V: 16 chunks (2 subs x 64 dh rows)
        int i   = (w << 2) + j;          // 0..15; sub = i>>3
        int c   = (i << 6) + lane;
        int dh  = (c >> 3) & 63;         // (i&7)*8 + lane>>3
        int k8  = (c & 7) ^ (dh & 7);
        const ushort_t* g = Vt + vbase + (size_t)dh * SEQ + ((i >> 3) << 6) + (k8 << 3);
        __builtin_amdgcn_global_load_lds(
            (const __attribute__((address_space(1))) unsigned int*)g,
            (__attribute__((address_space(3))) unsigned int*)(
                Vs[0] + ((i >> 3) << 12) + ((i & 7) << 9)),
            16, 0, 0);
    }
    __syncthreads();

    // qfrag[kc]: B-frag of Q^T — row = wave q-strip + l31, dh chunk kc*16+hi*8
    short8 qfrag[4];
    const int qrow = (w << 5) + l31;
    #pragma unroll
    for (int kc = 0; kc < 4; ++kc) {
        int slot = ((kc << 1) + hi) ^ (qrow & 7);
        qfrag[kc] = *(const short8*)(Qs + qrow * 64 + slot * 8);
    }

    floatx16 oacc[2] = {};              // [dhb]: O[q][dhb*32 + l31]
    float ds0 = 0.f, ds1 = 0.f, ds2 = 0.f, ds3 = 0.f;

    for (int kt = 0; kt < 16; ++kt) {
        const int cur = kt & 1;
        const int k0 = kt << 7;

        // ---- stage NEXT 128-key tile into the other buffer ----
        if (kt < 15) {
            const int k0n = (kt + 1) << 7;
            ushort_t* Kd = Ks[cur ^ 1];
            ushort_t* Vd = Vs[cur ^ 1];
            #pragma unroll
            for (int j = 0; j < 4; ++j) {    // K
                int i   = (w << 2) + j;
                int c   = (i << 6) + lane;
                int row = c >> 3;            // key 0..127
                int k8  = (c & 7) ^ (row & 7);
                const ushort_t* g = Kf + qkbase + (size_t)(k0n + row) * DF + (k8 << 3);
                __builtin_amdgcn_global_load_lds(
                    (const __attribute__((address_space(1))) unsigned int*)g,
                    (__attribute__((address_space(3))) unsigned int*)(
                        Kd + ((i >> 3) << 12) + ((i & 7) << 9)),
                    16, 0, 0);
            }
            #pragma unroll
            for (int j = 0; j < 4; ++j) {    // V
                int i   = (w << 2) + j;
                int c   = (i << 6) + lane;
                int dh  = (c >> 3) & 63;
                int k8  = (c & 7) ^ (dh & 7);
                const ushort_t* g = Vt + vbase + (size_t)dh * SEQ
                                  + k0n + ((i >> 3) << 6) + (k8 << 3);
                __builtin_amdgcn_global_load_lds(
                    (const __attribute__((address_space(1))) unsigned int*)g,
                    (__attribute__((address_space(3))) unsigned int*)(
                        Vd + ((i >> 3) << 12) + ((i & 7) << 9)),
                    16, 0, 0);
            }
        }

        // ---- two 64-key sub-tiles in one barrier window ----
        #pragma unroll
        for (int sub = 0; sub < 2; ++sub) {
            const ushort_t* Kc = Ks[cur] + (sub << 12);
            const ushort_t* Vc = Vs[cur] + (sub << 12);
            const int k0s = k0 + (sub << 6);

            // mask-bias loads for this sub (L1-hot after first pass)
            float mbf[2][16];
            #pragma unroll
            for (int kb = 0; kb < 2; ++kb)
                #pragma unroll
                for (int u = 0; u < 4; ++u) {
                    float4 v = *(const float4*)(
                        maskb + mbase + k0s + (kb << 5) + (u << 3) + (hi << 2));
                    mbf[kb][(u << 2) + 0] = v.x;
                    mbf[kb][(u << 2) + 1] = v.y;
                    mbf[kb][(u << 2) + 2] = v.z;
                    mbf[kb][(u << 2) + 3] = v.w;
                }

            // S^T = K·Q^T: sacc[kb] = S^T[kb*32 + rows][q]
            floatx16 sacc[2] = {};
            #pragma unroll
            for (int kc = 0; kc < 4; ++kc) {
                #pragma unroll
                for (int kb = 0; kb < 2; ++kb) {
                    int row  = (kb << 5) + l31;
                    int slot = ((kc << 1) + hi) ^ (row & 7);
                    short8 kf = *(const short8*)(Kc + row * 64 + slot * 8);
                    sacc[kb] = __builtin_amdgcn_mfma_f32_32x32x16_bf16(
                        kf, qfrag[kc], sacc[kb], 0, 0, 0);
                }
            }

            // softmax + cvt_pk + permlane32_swap -> PV A-frags
            short8 pa[4];
            #pragma unroll
            for (int kb = 0; kb < 2; ++kb) {
                float p[16];
                #pragma unroll
                for (int r = 0; r < 16; ++r)
                    p[r] = exp2_fast(sacc[kb][r] + mbf[kb][r]);
                ds0 += (p[0] + p[1])  + (p[2] + p[3]);
                ds1 += (p[4] + p[5])  + (p[6] + p[7]);
                ds2 += (p[8] + p[9])  + (p[10] + p[11]);
                ds3 += (p[12] + p[13]) + (p[14] + p[15]);
                unsigned int pk[8];
                #pragma unroll
                for (int i = 0; i < 8; ++i)
                    asm("v_cvt_pk_bf16_f32 %0, %1, %2"
                        : "=v"(pk[i]) : "v"(p[2 * i]), "v"(p[2 * i + 1]));
                #pragma unroll
                for (int cc = 0; cc < 2; ++cc) {
                    unsigned int a0 = pk[(cc << 2) + 0], b0 = pk[(cc << 2) + 2];
                    unsigned int a1 = pk[(cc << 2) + 1], b1 = pk[(cc << 2) + 3];
                    asm("v_permlane32_swap_b32 %0, %1" : "+v"(a0), "+v"(b0));
                    asm("v_permlane32_swap_b32 %0, %1" : "+v"(a1), "+v"(b1));
                    union { unsigned int u[4]; short8 s; } pu;
                    pu.u[0] = a0; pu.u[1] = a1; pu.u[2] = b0; pu.u[3] = b1;
                    pa[(kb << 1) + cc] = pu.s;
                }
            }

            // PV: O[q][dh] += P · V
            #pragma unroll
            for (int kc2 = 0; kc2 < 4; ++kc2) {
                #pragma unroll
                for (int dhb = 0; dhb < 2; ++dhb) {
                    int row  = (dhb << 5) + l31;
                    int slot = ((kc2 << 1) + hi) ^ (row & 7);
                    short8 vf = *(const short8*)(Vc + row * 64 + slot * 8);
                    oacc[dhb] = __builtin_amdgcn_mfma_f32_32x32x16_bf16(
                        pa[kc2], vf, oacc[dhb], 0, 0, 0);
                }
            }
        }

        __syncthreads();   // next tile staged & visible; cur-buf reads drained
    }

    // ---- epilogue ----
    float dsum = (ds0 + ds1) + (ds2 + ds3);   // partial for q = w*32 + l31
    dsum += __shfl_xor(dsum, 32, 64);         // hi halves hold complementary keys
    float rdv = 1.0f / dsum;

    // share rdv across the 4*hi+reg q-pattern via dead Qs (wave-local region)
    float* dls = (float*)Qs + (w << 5);       // 32 floats per wave
    dls[l31] = rdv;                           // both hi halves write same value
    float4 rv[4];
    #pragma unroll
    for (int u = 0; u < 4; ++u)
        rv[u] = *(const float4*)(dls + (u << 3) + (hi << 2));

    #pragma unroll
    for (int u = 0; u < 4; ++u) {
        #pragma unroll
        for (int r2 = 0; r2 < 4; ++r2) {
            const int q = q0 + (w << 5) + (u << 3) + (hi << 2) + r2;
            const float rr = (r2 == 0) ? rv[u].x : (r2 == 1) ? rv[u].y
                           : (r2 == 2) ? rv[u].z : rv[u].w;
            #pragma unroll
            for (int dhb = 0; dhb < 2; ++dhb)
                Xr[qkbase + (size_t)q * DF + (dhb << 5) + l31] =
                    f2bf(oacc[dhb][(u << 2) + r2] * rr);
        }
    }
}

// ---------------------------------------------------------------------------
extern "C" void kernel_launch(void* const* d_in, const int* in_sizes, int n_in,
                              void* d_out, int out_size, void* d_ws, size_t ws_size,
                              hipStream_t stream)
{
    const float* Q    = (const float*)d_in[0];
    const float* K    = (const float*)d_in[1];
    const float* V    = (const float*)d_in[2];
    const int*   mask = (const int*)d_in[3];
    const float* Wq   = (const float*)d_in[4];
    const float* bq   = (const float*)d_in[5];
    const float* Wk   = (const float*)d_in[6];
    const float* bk   = (const float*)d_in[7];
    const float* Wv   = (const float*)d_in[8];
    const float* bv   = (const float*)d_in[9];
    const float* Wo   = (const float*)d_in[10];
    const float* bo   = (const float*)d_in[11];
    float* out = (float*)d_out;

    // ws (48 MB): Wcat 8 + Qf 8 + Kf 8 + Vt 8 + Xr 8 + Qb 8.
    // Aliases: Kb = Xr (dead before attn writes), Vb = d_out (first 8 MB,
    // dead before gemm_out writes), maskb = d_out second half (16 KB; attn
    // reads it before gemm_out overwrites d_out — stream-ordered).
    ushort_t* Wqb = (ushort_t*)d_ws;
    ushort_t* Wkb = Wqb + (1 << 20);
    ushort_t* Wvb = Wkb + (1 << 20);
    ushort_t* Wob = Wvb + (1 << 20);
    ushort_t* Qf  = Wob + (1 << 20);
    ushort_t* Kf  = Qf + (size_t)MROWS * DF;
    ushort_t* Vt  = Kf + (size_t)MROWS * DF;
    ushort_t* Xr  = Vt + (size_t)MROWS * DF;
    ushort_t* Qb  = Xr + (size_t)MROWS * DF;
    ushort_t* Kb  = Xr;
    ushort_t* Vb  = (ushort_t*)d_out;
    float*    maskb = (float*)((ushort_t*)d_out + (size_t)(1 << 22));  // +8 MB

    const int nin = MROWS * DF;  // 4M
    const int nw  = DF * DF;     // 1M

    CvtArgs ca;
    ca.src[0] = Q;  ca.dst[0] = Qb;  ca.n[0] = nin;
    ca.src[1] = K;  ca.dst[1] = Kb;  ca.n[1] = nin;
    ca.src[2] = V;  ca.dst[2] = Vb;  ca.n[2] = nin;
    ca.src[3] = Wq; ca.dst[3] = Wqb; ca.n[3] = nw;
    ca.src[4] = Wk; ca.dst[4] = Wkb; ca.n[4] = nw;
    ca.src[5] = Wv; ca.dst[5] = Wvb; ca.n[5] = nw;
    ca.src[6] = Wo; ca.dst[6] = Wob; ca.n[6] = nw;
    ca.msrc = mask;
    ca.mdst = maskb;

    dim3 blk(256);
    cvt_all<<<dim3(nin / 1024, 8), blk, 0, stream>>>(ca);

    gemm_qkv<<<dim3(768), blk, 0, stream>>>(Qb, Kb, Vb, Wqb, bq, bk, bv,
                                            Qf, Kf, Vt);

    attn_mfma<<<dim3(512), blk, 0, stream>>>(Qf, Kf, Vt, maskb, Xr);

    gemm_out<<<dim3(512), blk, 0, stream>>>(Xr, Wob, bo, out);
}

// Round 8
// 226.814 us; speedup vs baseline: 1.5049x; 1.0110x over previous
//
#include <hip/hip_runtime.h>

// MultiHeadedAttention B=2,S=2048,D=1024,H=16,Dh=64 — f32 in/out.
// Round 15:
//   - cvt_all: packed 1-D grid (8194 blocks, ALL full; was 32768 with 16.4k
//     empty). 8 elems/thread: 2x float4 load + 1x 16B store.
//   - attn: staging/mask addresses hoisted to incrementing pointers (kills
//     ~40 addr-VALU/iter/wave); sub-tiles reordered QK0,QK1 -> SM0,PV0 ->
//     SM1,PV1 so PV0 MFMA co-issues with SM1 exp (independent pipes).
//   - GEMMs: setprio removed (m190: slightly negative on lockstep GEMM).
// R14: 128-key staging, 2 subs/barrier. R13: 32x32x16 MFMA, in-register P
// (cvt_pk + permlane32_swap). R12: GEMMs XCD-chunked 1-D grids. R11: attn
// XCD co-location (FETCH 69.7->12.4 MB verified). R8: exp2 softmax (log2e/32
// folded into Q), mask-bias plane. Frag layouts + XOR-slot swizzle
// HW-verified (rounds 3-6, m74/m101).

typedef unsigned short ushort_t;
typedef __attribute__((ext_vector_type(8)))  short short8;
typedef __attribute__((ext_vector_type(4)))  float floatx4;
typedef __attribute__((ext_vector_type(16))) float floatx16;

#define BATCH 2
#define SEQ   2048
#define DF    1024
#define NH    16
#define DH    64
#define MROWS 4096

__device__ __forceinline__ ushort_t f2bf(float f) {
    unsigned int u = __float_as_uint(f);
    u += 0x7FFFu + ((u >> 16) & 1u);   // RNE
    return (ushort_t)(u >> 16);
}

__device__ __forceinline__ float exp2_fast(float x) {
    float r; asm("v_exp_f32 %0, %1" : "=v"(r) : "v"(x)); return r;
}

// ---------------------------------------------------------------------------
// Fused f32->bf16 conversion of 7 tensors + int-mask -> float-bias plane.
// Packed 1-D grid, 2048 elems/block (256 thr x 8):
//   blocks [0,6144):    planes 0-2 (Q,K,V; 4M elems -> 2048 blocks each)
//   blocks [6144,8192): planes 3-6 (weights; 1M elems -> 512 blocks each)
//   blocks [8192,8194): mask plane (4096 ints -> float bias)
// ---------------------------------------------------------------------------
struct CvtArgs {
    const float* src[7];
    ushort_t*    dst[7];
    const int*   msrc;   // int mask  [B*S]
    float*       mdst;   // float bias [B*S]: mask? 0 : -1e9
};

__global__ __launch_bounds__(256) void cvt_all(CvtArgs a)
{
    const int bx  = blockIdx.x;
    const int tid = threadIdx.x;

    if (bx >= 8192) {                       // mask plane
        int i = ((bx - 8192) * 256 + tid) * 8;
        int4 m0 = *(const int4*)(a.msrc + i);
        int4 m1 = *(const int4*)(a.msrc + i + 4);
        float4 o0, o1;
        o0.x = m0.x ? 0.f : -1e9f;  o0.y = m0.y ? 0.f : -1e9f;
        o0.z = m0.z ? 0.f : -1e9f;  o0.w = m0.w ? 0.f : -1e9f;
        o1.x = m1.x ? 0.f : -1e9f;  o1.y = m1.y ? 0.f : -1e9f;
        o1.z = m1.z ? 0.f : -1e9f;  o1.w = m1.w ? 0.f : -1e9f;
        *(float4*)(a.mdst + i)     = o0;
        *(float4*)(a.mdst + i + 4) = o1;
        return;
    }

    int pl, i;
    if (bx < 6144) { pl = bx >> 11;                i = ((bx & 2047) * 256 + tid) * 8; }
    else           { pl = 3 + ((bx - 6144) >> 9);  i = (((bx - 6144) & 511) * 256 + tid) * 8; }

    const float* in  = a.src[pl];
    ushort_t*    out = a.dst[pl];
    float4 v0 = *(const float4*)(in + i);
    float4 v1 = *(const float4*)(in + i + 4);
    union { ushort_t u[8]; uint4 q; } o;
    o.u[0] = f2bf(v0.x); o.u[1] = f2bf(v0.y); o.u[2] = f2bf(v0.z); o.u[3] = f2bf(v0.w);
    o.u[4] = f2bf(v1.x); o.u[5] = f2bf(v1.y); o.u[6] = f2bf(v1.z); o.u[7] = f2bf(v1.w);
    *(uint4*)(out + i) = o.q;
}

// ---------------------------------------------------------------------------
// Fused QKV projections, all-bf16 operands. 1-D grid 768, XCD-chunked:
//   xcd = f&7 owns by ∈ [4*xcd, 4*xcd+4) x all 24 n-blocks.
//   n0 <1024: Qf (A=Qb, bq, epilogue scale log2e/32)
//   <2048:    Kf (A=Kb, bk)
//   else:     Vt DIRECT (A=Vb, bv) — transposed write [(b*16+h)*64+dh][s].
// 128x128 tile, BK=64, global_load_lds staging, XOR-slot swizzle (verified).
// ---------------------------------------------------------------------------
__global__ __launch_bounds__(256) void gemm_qkv(
    const ushort_t* __restrict__ Qb, const ushort_t* __restrict__ Kb,
    const ushort_t* __restrict__ Vb, const ushort_t* __restrict__ Wcat,
    const float* __restrict__ bq, const float* __restrict__ bk,
    const float* __restrict__ bv,
    ushort_t* __restrict__ Qf, ushort_t* __restrict__ Kf,
    ushort_t* __restrict__ Vt)
{
    __shared__ ushort_t As[128 * 64];  // 16 KB, [row][slot], slot = k8 ^ (row&7)
    __shared__ ushort_t Bs[128 * 64];  // 16 KB

    const int t = threadIdx.x;
    const int lane = t & 63, w = t >> 6;
    const int x = lane & 15, y = lane >> 4;
    const int wm = (w >> 1) * 64, wn = (w & 1) * 64;

    const int f   = blockIdx.x;
    const int xcd = f & 7;
    const int idx = f >> 3;                     // 0..95
    const int m0  = (((xcd << 2) + (idx & 3)) << 7);
    const int n0  = (idx >> 2) << 7;            // 0..2944

    const ushort_t* Ab; const float* bp;
    if (n0 < 1024)      { Ab = Qb; bp = bq; }
    else if (n0 < 2048) { Ab = Kb; bp = bk; }
    else                { Ab = Vb; bp = bv; }
    const int ncol0 = n0 & 1023;

    floatx4 acc[4][4] = {};

    for (int kt = 0; kt < 16; ++kt) {
        const int k0 = kt * 64;

        #pragma unroll
        for (int j = 0; j < 4; ++j) {   // A stage
            int i   = (w << 2) + j;
            int c   = (i << 6) + lane;
            int row = c >> 3;
            int s   = c & 7;
            int k8  = s ^ (row & 7);
            const ushort_t* g = Ab + (size_t)(m0 + row) * DF + k0 + (k8 << 3);
            __builtin_amdgcn_global_load_lds(
                (const __attribute__((address_space(1))) unsigned int*)g,
                (__attribute__((address_space(3))) unsigned int*)(As + (i << 9)),
                16, 0, 0);
        }
        #pragma unroll
        for (int j = 0; j < 4; ++j) {   // B stage
            int i   = (w << 2) + j;
            int c   = (i << 6) + lane;
            int row = c >> 3;
            int s   = c & 7;
            int k8  = s ^ (row & 7);
            const ushort_t* g = Wcat + (size_t)(n0 + row) * DF + k0 + (k8 << 3);
            __builtin_amdgcn_global_load_lds(
                (const __attribute__((address_space(1))) unsigned int*)g,
                (__attribute__((address_space(3))) unsigned int*)(Bs + (i << 9)),
                16, 0, 0);
        }
        __syncthreads();

        #pragma unroll
        for (int kh = 0; kh < 2; ++kh) {
            const int slot = ((kh << 2) + y) ^ (x & 7);
            short8 af[4], bfr[4];
            #pragma unroll
            for (int mt = 0; mt < 4; ++mt)
                af[mt] = *(const short8*)(As + (wm + (mt << 4) + x) * 64 + slot * 8);
            #pragma unroll
            for (int nt = 0; nt < 4; ++nt)
                bfr[nt] = *(const short8*)(Bs + (wn + (nt << 4) + x) * 64 + slot * 8);
            #pragma unroll
            for (int mt = 0; mt < 4; ++mt)
                #pragma unroll
                for (int nt = 0; nt < 4; ++nt)
                    acc[mt][nt] = __builtin_amdgcn_mfma_f32_16x16x32_bf16(
                        af[mt], bfr[nt], acc[mt][nt], 0, 0, 0);
        }
        __syncthreads();
    }

    float bvv[4];
    #pragma unroll
    for (int nt = 0; nt < 4; ++nt) bvv[nt] = bp[ncol0 + wn + (nt << 4) + x];

    if (n0 < 2048) {
        ushort_t* outp = (n0 < 1024) ? Qf : Kf;
        const float osc = (n0 < 1024) ? 0.0450842200f : 1.0f;  // log2(e)/32
        #pragma unroll
        for (int mt = 0; mt < 4; ++mt) {
            #pragma unroll
            for (int r = 0; r < 4; ++r) {
                const size_t grow = (size_t)(m0 + wm + (mt << 4) + (y << 2) + r) * DF;
                #pragma unroll
                for (int nt = 0; nt < 4; ++nt)
                    outp[grow + ncol0 + wn + (nt << 4) + x] =
                        f2bf((acc[mt][nt][r] + bvv[nt]) * osc);
            }
        }
    } else {
        // V: direct transposed write to Vt[(b*16+h)*64+dh][s]
        #pragma unroll
        for (int mt = 0; mt < 4; ++mt) {
            int m   = m0 + wm + (mt << 4) + (y << 2);  // +r are consecutive s
            int bb2 = m >> 11;
            int s0  = m & 2047;
            #pragma unroll
            for (int nt = 0; nt < 4; ++nt) {
                int col = ncol0 + wn + (nt << 4) + x;  // h*64+dh
                ushort4 pk;
                pk.x = f2bf(acc[mt][nt][0] + bvv[nt]);
                pk.y = f2bf(acc[mt][nt][1] + bvv[nt]);
                pk.z = f2bf(acc[mt][nt][2] + bvv[nt]);
                pk.w = f2bf(acc[mt][nt][3] + bvv[nt]);
                *(ushort4*)(Vt + ((size_t)(bb2 << 10) + col) * 2048 + s0) = pk;
            }
        }
    }
}

// ---------------------------------------------------------------------------
// Out-projection: C[4096,1024] = Xr @ Wo^T + bo, f32 out.
// 1-D grid 512, XCD-chunked. Tile 128(M) x 64(N). Wave-tile 64x32.
// ---------------------------------------------------------------------------
__global__ __launch_bounds__(256) void gemm_out(
    const ushort_t* __restrict__ Xr, const ushort_t* __restrict__ Wb,
    const float* __restrict__ bias, float* __restrict__ C)
{
    __shared__ ushort_t As[128 * 64];  // 16 KB
    __shared__ ushort_t Bs[64 * 64];   // 8 KB

    const int t = threadIdx.x;
    const int lane = t & 63, w = t >> 6;
    const int x = lane & 15, y = lane >> 4;
    const int wm = (w >> 1) * 64, wn = (w & 1) * 32;

    const int f   = blockIdx.x;
    const int xcd = f & 7;
    const int idx = f >> 3;                    // 0..63
    const int m0  = (((xcd << 2) + (idx & 3)) << 7);
    const int n0  = (idx >> 2) << 6;           // 0..960

    floatx4 acc[4][2] = {};

    for (int kt = 0; kt < 16; ++kt) {
        const int k0 = kt * 64;

        #pragma unroll
        for (int j = 0; j < 4; ++j) {   // A stage: 16 KB
            int i   = (w << 2) + j;
            int c   = (i << 6) + lane;
            int row = c >> 3;
            int s   = c & 7;
            int k8  = s ^ (row & 7);
            const ushort_t* g = Xr + (size_t)(m0 + row) * DF + k0 + (k8 << 3);
            __builtin_amdgcn_global_load_lds(
                (const __attribute__((address_space(1))) unsigned int*)g,
                (__attribute__((address_space(3))) unsigned int*)(As + (i << 9)),
                16, 0, 0);
        }
        #pragma unroll
        for (int j = 0; j < 2; ++j) {   // B stage: 8 KB
            int i   = (w << 1) + j;
            int c   = (i << 6) + lane;
            int row = c >> 3;
            int s   = c & 7;
            int k8  = s ^ (row & 7);
            const ushort_t* g = Wb + (size_t)(n0 + row) * DF + k0 + (k8 << 3);
            __builtin_amdgcn_global_load_lds(
                (const __attribute__((address_space(1))) unsigned int*)g,
                (__attribute__((address_space(3))) unsigned int*)(Bs + (i << 9)),
                16, 0, 0);
        }
        __syncthreads();

        #pragma unroll
        for (int kh = 0; kh < 2; ++kh) {
            const int slot = ((kh << 2) + y) ^ (x & 7);
            short8 af[4], bfr[2];
            #pragma unroll
            for (int mt = 0; mt < 4; ++mt)
                af[mt] = *(const short8*)(As + (wm + (mt << 4) + x) * 64 + slot * 8);
            #pragma unroll
            for (int nt = 0; nt < 2; ++nt)
                bfr[nt] = *(const short8*)(Bs + (wn + (nt << 4) + x) * 64 + slot * 8);
            #pragma unroll
            for (int mt = 0; mt < 4; ++mt)
                #pragma unroll
                for (int nt = 0; nt < 2; ++nt)
                    acc[mt][nt] = __builtin_amdgcn_mfma_f32_16x16x32_bf16(
                        af[mt], bfr[nt], acc[mt][nt], 0, 0, 0);
        }
        __syncthreads();
    }

    float bvv[2];
    #pragma unroll
    for (int nt = 0; nt < 2; ++nt) bvv[nt] = bias[n0 + wn + (nt << 4) + x];

    #pragma unroll
    for (int mt = 0; mt < 4; ++mt) {
        #pragma unroll
        for (int r = 0; r < 4; ++r) {
            const size_t grow = (size_t)(m0 + wm + (mt << 4) + (y << 2) + r) * DF;
            #pragma unroll
            for (int nt = 0; nt < 2; ++nt)
                C[grow + n0 + wn + (nt << 4) + x] = acc[mt][nt][r] + bvv[nt];
        }
    }
}

// ---------------------------------------------------------------------------
// Attention v3.1: 32x32x16 MFMA, in-register P, 128-key staging, hoisted
// staging pointers, QK-both-subs-first schedule (PV0 MFMA ∥ SM1 VALU).
// Block = 4 waves x 32 q = 128 q; grid 512 = 16 qb x 32 hb (XCD co-located).
// LDS 80 KB: Qs 16 + Ks dbuf 32 + Vs dbuf 32 (2 blocks/CU, grid-capped).
// ---------------------------------------------------------------------------
__global__ __launch_bounds__(256) void attn_mfma(
    const ushort_t* __restrict__ Qf, const ushort_t* __restrict__ Kf,
    const ushort_t* __restrict__ Vt, const float* __restrict__ maskb,
    ushort_t* __restrict__ Xr)
{
    __shared__ ushort_t Qs[128 * 64];       // 16 KB; rdv scratch in epilogue
    __shared__ ushort_t Ks[2][2 * 64 * 64]; // 32 KB double-buffered, 2 subs
    __shared__ ushort_t Vs[2][2 * 64 * 64]; // 32 KB double-buffered, 2 subs

    const int t = threadIdx.x;
    const int lane = t & 63, w = t >> 6;
    const int l31 = lane & 31, hi = lane >> 5;

    const int f  = blockIdx.x;
    const int hb = f & 31;          // b*16 + h
    const int b  = hb >> 4;
    const int h  = hb & 15;
    const int q0 = (f >> 5) << 7;   // 128-q block base

    const size_t qkbase = ((size_t)b * SEQ) * DF + (size_t)h * DH;
    const size_t vbase  = ((size_t)(b * NH + h) * DH) * SEQ;
    const int mbase = b * SEQ;

    // ---- hoisted staging descriptors (advance by one 128-key tile/iter) ----
    const ushort_t* gk[4];
    const ushort_t* gv[4];
    unsigned lds_off[4];
    #pragma unroll
    for (int j = 0; j < 4; ++j) {
        int i    = (w << 2) + j;                 // chunk 0..15
        int krow = (i << 3) + (lane >> 3);       // key row 0..127
        int kk8  = (lane & 7) ^ (krow & 7);
        gk[j] = Kf + qkbase + (size_t)krow * DF + (kk8 << 3);
        int dh   = ((i & 7) << 3) + (lane >> 3); // 0..63
        int vk8  = (lane & 7) ^ (dh & 7);
        gv[j] = Vt + vbase + (size_t)dh * SEQ + ((i >> 3) << 6) + (vk8 << 3);
        lds_off[j] = ((i >> 3) << 12) + ((i & 7) << 9);
    }
    const float* mp = maskb + mbase + (hi << 2);

    // ---- prologue: Q stage (16 KB) + K/V tile 0 ----
    #pragma unroll
    for (int j = 0; j < 4; ++j) {
        int i   = (w << 2) + j;          // 0..15
        int c   = (i << 6) + lane;
        int row = c >> 3;                // 0..127
        int k8  = (c & 7) ^ (row & 7);
        const ushort_t* g = Qf + qkbase + (size_t)(q0 + row) * DF + (k8 << 3);
        __builtin_amdgcn_global_load_lds(
            (const __attribute__((address_space(1))) unsigned int*)g,
            (__attribute__((address_space(3))) unsigned int*)(Qs + (i << 9)),
            16, 0, 0);
    }
    #pragma unroll
    for (int j = 0; j < 4; ++j) {
        __builtin_amdgcn_global_load_lds(
            (const __attribute__((address_space(1))) unsigned int*)gk[j],
            (__attribute__((address_space(3))) unsigned int*)(Ks[0] + lds_off[j]),
            16, 0, 0);
        gk[j] += (size_t)128 * DF;
        __builtin_amdgcn_global_load_lds(
            (const __attribute__((address_space(1))) unsigned int*)gv[j],
            (__attribute__((address_space(3))) unsigned int*)(Vs[0] + lds_off[j]),
            16, 0, 0);
        gv[j] += 128;
    }
    __syncthreads();

    // qfrag[kc]: B-frag of Q^T — row = wave q-strip + l31, dh chunk kc*16+hi*8
    short8 qfrag[4];
    const int qrow = (w << 5) + l31;
    #pragma unroll
    for (int kc = 0; kc < 4; ++kc) {
        int slot = ((kc << 1) + hi) ^ (qrow & 7);
        qfrag[kc] = *(const short8*)(Qs + qrow * 64 + slot * 8);
    }

    floatx16 oacc[2] = {};              // [dhb]: O[q][dhb*32 + l31]
    float ds0 = 0.f, ds1 = 0.f, ds2 = 0.f, ds3 = 0.f;

    for (int kt = 0; kt < 16; ++kt) {
        const int cur = kt & 1;

        // ---- stage NEXT 128-key tile into the other buffer ----
        if (kt < 15) {
            ushort_t* Kd = Ks[cur ^ 1];
            ushort_t* Vd = Vs[cur ^ 1];
            #pragma unroll
            for (int j = 0; j < 4; ++j) {
                __builtin_amdgcn_global_load_lds(
                    (const __attribute__((address_space(1))) unsigned int*)gk[j],
                    (__attribute__((address_space(3))) unsigned int*)(Kd + lds_off[j]),
                    16, 0, 0);
                gk[j] += (size_t)128 * DF;
                __builtin_amdgcn_global_load_lds(
                    (const __attribute__((address_space(1))) unsigned int*)gv[j],
                    (__attribute__((address_space(3))) unsigned int*)(Vd + lds_off[j]),
                    16, 0, 0);
                gv[j] += 128;
            }
        }

        // ---- QK^T for BOTH subs first (fills MFMA pipe before VALU) ----
        floatx16 sacc[2][2] = {};       // [sub][kb]; fully unrolled (no scratch)
        #pragma unroll
        for (int sub = 0; sub < 2; ++sub) {
            const ushort_t* Kc = Ks[cur] + (sub << 12);
            #pragma unroll
            for (int kc = 0; kc < 4; ++kc) {
                #pragma unroll
                for (int kb = 0; kb < 2; ++kb) {
                    int row  = (kb << 5) + l31;
                    int slot = ((kc << 1) + hi) ^ (row & 7);
                    short8 kf = *(const short8*)(Kc + row * 64 + slot * 8);
                    sacc[sub][kb] = __builtin_amdgcn_mfma_f32_32x32x16_bf16(
                        kf, qfrag[kc], sacc[sub][kb], 0, 0, 0);
                }
            }
        }

        // ---- SM0 -> PV0, SM1 -> PV1 (PV0 MFMA overlaps SM1 VALU) ----
        #pragma unroll
        for (int sub = 0; sub < 2; ++sub) {
            const ushort_t* Vc = Vs[cur] + (sub << 12);

            float mbf[2][16];
            #pragma unroll
            for (int kb = 0; kb < 2; ++kb)
                #pragma unroll
                for (int u = 0; u < 4; ++u) {
                    float4 v = *(const float4*)(
                        mp + (sub << 6) + (kb << 5) + (u << 3));
                    mbf[kb][(u << 2) + 0] = v.x;
                    mbf[kb][(u << 2) + 1] = v.y;
                    mbf[kb][(u << 2) + 2] = v.z;
                    mbf[kb][(u << 2) + 3] = v.w;
                }

            short8 pa[4];
            #pragma unroll
            for (int kb = 0; kb < 2; ++kb) {
                float p[16];
                #pragma unroll
                for (int r = 0; r < 16; ++r)
                    p[r] = exp2_fast(sacc[sub][kb][r] + mbf[kb][r]);
                ds0 += (p[0] + p[1])  + (p[2] + p[3]);
                ds1 += (p[4] + p[5])  + (p[6] + p[7]);
                ds2 += (p[8] + p[9])  + (p[10] + p[11]);
                ds3 += (p[12] + p[13]) + (p[14] + p[15]);
                unsigned int pk[8];
                #pragma unroll
                for (int i = 0; i < 8; ++i)
                    asm("v_cvt_pk_bf16_f32 %0, %1, %2"
                        : "=v"(pk[i]) : "v"(p[2 * i]), "v"(p[2 * i + 1]));
                #pragma unroll
                for (int cc = 0; cc < 2; ++cc) {
                    unsigned int a0 = pk[(cc << 2) + 0], b0 = pk[(cc << 2) + 2];
                    unsigned int a1 = pk[(cc << 2) + 1], b1 = pk[(cc << 2) + 3];
                    asm("v_permlane32_swap_b32 %0, %1" : "+v"(a0), "+v"(b0));
                    asm("v_permlane32_swap_b32 %0, %1" : "+v"(a1), "+v"(b1));
                    union { unsigned int u[4]; short8 s; } pu;
                    pu.u[0] = a0; pu.u[1] = a1; pu.u[2] = b0; pu.u[3] = b1;
                    pa[(kb << 1) + cc] = pu.s;
                }
            }

            #pragma unroll
            for (int kc2 = 0; kc2 < 4; ++kc2) {
                #pragma unroll
                for (int dhb = 0; dhb < 2; ++dhb) {
                    int row  = (dhb << 5) + l31;
                    int slot = ((kc2 << 1) + hi) ^ (row & 7);
                    short8 vf = *(const short8*)(Vc + row * 64 + slot * 8);
                    oacc[dhb] = __builtin_amdgcn_mfma_f32_32x32x16_bf16(
                        pa[kc2], vf, oacc[dhb], 0, 0, 0);
                }
            }
        }

        mp += 128;
        __syncthreads();   // next tile staged & visible; cur-buf reads drained
    }

    // ---- epilogue ----
    float dsum = (ds0 + ds1) + (ds2 + ds3);   // partial for q = w*32 + l31
    dsum += __shfl_xor(dsum, 32, 64);         // hi halves hold complementary keys
    float rdv = 1.0f / dsum;

    // share rdv across the 4*hi+reg q-pattern via dead Qs (wave-local region)
    float* dls = (float*)Qs + (w << 5);       // 32 floats per wave
    dls[l31] = rdv;                           // both hi halves write same value
    float4 rv[4];
    #pragma unroll
    for (int u = 0; u < 4; ++u)
        rv[u] = *(const float4*)(dls + (u << 3) + (hi << 2));

    #pragma unroll
    for (int u = 0; u < 4; ++u) {
        #pragma unroll
        for (int r2 = 0; r2 < 4; ++r2) {
            const int q = q0 + (w << 5) + (u << 3) + (hi << 2) + r2;
            const float rr = (r2 == 0) ? rv[u].x : (r2 == 1) ? rv[u].y
                           : (r2 == 2) ? rv[u].z : rv[u].w;
            #pragma unroll
            for (int dhb = 0; dhb < 2; ++dhb)
                Xr[qkbase + (size_t)q * DF + (dhb << 5) + l31] =
                    f2bf(oacc[dhb][(u << 2) + r2] * rr);
        }
    }
}

// ---------------------------------------------------------------------------
extern "C" void kernel_launch(void* const* d_in, const int* in_sizes, int n_in,
                              void* d_out, int out_size, void* d_ws, size_t ws_size,
                              hipStream_t stream)
{
    const float* Q    = (const float*)d_in[0];
    const float* K    = (const float*)d_in[1];
    const float* V    = (const float*)d_in[2];
    const int*   mask = (const int*)d_in[3];
    const float* Wq   = (const float*)d_in[4];
    const float* bq   = (const float*)d_in[5];
    const float* Wk   = (const float*)d_in[6];
    const float* bk   = (const float*)d_in[7];
    const float* Wv   = (const float*)d_in[8];
    const float* bv   = (const float*)d_in[9];
    const float* Wo   = (const float*)d_in[10];
    const float* bo   = (const float*)d_in[11];
    float* out = (float*)d_out;

    // ws (48 MB): Wcat 8 + Qf 8 + Kf 8 + Vt 8 + Xr 8 + Qb 8.
    // Aliases: Kb = Xr (dead before attn writes), Vb = d_out (first 8 MB,
    // dead before gemm_out writes), maskb = d_out second half (16 KB; attn
    // reads it before gemm_out overwrites d_out — stream-ordered).
    ushort_t* Wqb = (ushort_t*)d_ws;
    ushort_t* Wkb = Wqb + (1 << 20);
    ushort_t* Wvb = Wkb + (1 << 20);
    ushort_t* Wob = Wvb + (1 << 20);
    ushort_t* Qf  = Wob + (1 << 20);
    ushort_t* Kf  = Qf + (size_t)MROWS * DF;
    ushort_t* Vt  = Kf + (size_t)MROWS * DF;
    ushort_t* Xr  = Vt + (size_t)MROWS * DF;
    ushort_t* Qb  = Xr + (size_t)MROWS * DF;
    ushort_t* Kb  = Xr;
    ushort_t* Vb  = (ushort_t*)d_out;
    float*    maskb = (float*)((ushort_t*)d_out + (size_t)(1 << 22));  // +8 MB

    CvtArgs ca;
    ca.src[0] = Q;  ca.dst[0] = Qb;
    ca.src[1] = K;  ca.dst[1] = Kb;
    ca.src[2] = V;  ca.dst[2] = Vb;
    ca.src[3] = Wq; ca.dst[3] = Wqb;
    ca.src[4] = Wk; ca.dst[4] = Wkb;
    ca.src[5] = Wv; ca.dst[5] = Wvb;
    ca.src[6] = Wo; ca.dst[6] = Wob;
    ca.msrc = mask;
    ca.mdst = maskb;

    dim3 blk(256);
    cvt_all<<<dim3(8194), blk, 0, stream>>>(ca);

    gemm_qkv<<<dim3(768), blk, 0, stream>>>(Qb, Kb, Vb, Wqb, bq, bk, bv,
                                            Qf, Kf, Vt);

    attn_mfma<<<dim3(512), blk, 0, stream>>>(Qf, Kf, Vt, maskb, Xr);

    gemm_out<<<dim3(512), blk, 0, stream>>>(Xr, Wob, bo, out);
}